// Round 3
// baseline (1063.129 us; speedup 1.0000x reference)
//
#include <hip/hip_runtime.h>
#include <stddef.h>

// Problem constants
#define BB   8
#define TT_  2048
#define DD   768
#define VQ_  64
#define L2C  12
#define HID_ 1024
#define KK   4096
#define NMID 4
#define NT   (BB*TT_)         // 16384 positions

// ---------------------------------------------------------------------------
// 1) bits @ mlp_w_in.T + b_in  ->  X [K, HID]
// grid (HID/256, K/16), block 256
__global__ __launch_bounds__(256) void k_mlp_in(const float* __restrict__ w_in,
                                                const float* __restrict__ b_in,
                                                float* __restrict__ X) {
    __shared__ float ws_[256 * 12];
    __shared__ float bs_[256];
    int tid = threadIdx.x;
    int h0  = blockIdx.x * 256;
    for (int i = tid; i < 256 * 12; i += 256) ws_[i] = w_in[h0 * 12 + i];
    bs_[tid] = b_in[h0 + tid];
    __syncthreads();
    float w[12];
#pragma unroll
    for (int l = 0; l < 12; l++) w[l] = ws_[tid * 12 + l];
    float bias = bs_[tid];
    int k0 = blockIdx.y * 16;
    for (int kk = 0; kk < 16; kk++) {
        int k = k0 + kk;
        float acc = bias;
#pragma unroll
        for (int l = 0; l < 12; l++)
            if ((k >> (11 - l)) & 1) acc += w[l];
        X[(size_t)k * HID_ + h0 + tid] = acc;
    }
}

// ---------------------------------------------------------------------------
// 2) BatchNorm statistics: mean/var per column over K rows. grid HID, block 256
__global__ __launch_bounds__(256) void k_bn_stats(const float* __restrict__ X,
                                                  float* __restrict__ mv) {
    int c = blockIdx.x, tid = threadIdx.x;
    float s = 0.f, s2 = 0.f;
    for (int r = tid; r < KK; r += 256) {
        float v = X[(size_t)r * HID_ + c];
        s += v; s2 += v * v;
    }
    __shared__ float sh[256], sh2[256];
    sh[tid] = s; sh2[tid] = s2;
    __syncthreads();
    for (int off = 128; off; off >>= 1) {
        if (tid < off) { sh[tid] += sh[tid + off]; sh2[tid] += sh2[tid + off]; }
        __syncthreads();
    }
    if (tid == 0) {
        float m = sh[0] * (1.f / KK);
        float v = sh2[0] * (1.f / KK) - m * m;
        mv[c] = m; mv[HID_ + c] = v;
    }
}

// ---------------------------------------------------------------------------
// 3) BN apply + ReLU (in place). grid K*HID/1024, block 256 (float4/thread)
__global__ __launch_bounds__(256) void k_bn_apply(float* __restrict__ X,
                                                  const float* __restrict__ mv,
                                                  const float* __restrict__ gamma,
                                                  const float* __restrict__ beta) {
    int i = blockIdx.x * 256 + threadIdx.x;       // float4 index
    int c = (i << 2) & (HID_ - 1);
    float4 x = ((const float4*)X)[i];
    float4 m = *(const float4*)(mv + c);
    float4 v = *(const float4*)(mv + HID_ + c);
    float4 g = *(const float4*)(gamma + c);
    float4 b = *(const float4*)(beta + c);
    float4 o;
    o.x = fmaxf(0.f, (x.x - m.x) * (1.f / sqrtf(v.x + 1e-5f)) * g.x + b.x);
    o.y = fmaxf(0.f, (x.y - m.y) * (1.f / sqrtf(v.y + 1e-5f)) * g.y + b.y);
    o.z = fmaxf(0.f, (x.z - m.z) * (1.f / sqrtf(v.z + 1e-5f)) * g.z + b.z);
    o.w = fmaxf(0.f, (x.w - m.w) * (1.f / sqrtf(v.w + 1e-5f)) * g.w + b.w);
    ((float4*)X)[i] = o;
}

// ---------------------------------------------------------------------------
// 4) C[M,N] = A[M,Kd] @ W[N,Kd]^T + bias[N].  All fp32.
// 64x64 tile, BK=16, block 256 (4x4 per thread). grid (M/64, N/64)
__global__ __launch_bounds__(256) void k_gemm(const float* __restrict__ A,
                                              const float* __restrict__ W,
                                              const float* __restrict__ bias,
                                              float* __restrict__ C,
                                              int M, int N, int Kd) {
    __shared__ float As[16][68];
    __shared__ float Bs[16][68];
    int tid = threadIdx.x;
    int m0 = blockIdx.x * 64, n0 = blockIdx.y * 64;
    int lr = tid >> 2;            // 0..63
    int lk = (tid & 3) << 2;      // 0,4,8,12
    int tx = tid & 15, ty = tid >> 4;
    float acc[4][4] = {};
    for (int k0 = 0; k0 < Kd; k0 += 16) {
        float4 av = *(const float4*)(A + (size_t)(m0 + lr) * Kd + k0 + lk);
        float4 wv = *(const float4*)(W + (size_t)(n0 + lr) * Kd + k0 + lk);
        __syncthreads();
        As[lk + 0][lr] = av.x; As[lk + 1][lr] = av.y;
        As[lk + 2][lr] = av.z; As[lk + 3][lr] = av.w;
        Bs[lk + 0][lr] = wv.x; Bs[lk + 1][lr] = wv.y;
        Bs[lk + 2][lr] = wv.z; Bs[lk + 3][lr] = wv.w;
        __syncthreads();
#pragma unroll
        for (int k = 0; k < 16; k++) {
            const float4 a4 = *(const float4*)&As[k][ty << 2];
            const float4 b4 = *(const float4*)&Bs[k][tx << 2];
            float a[4] = {a4.x, a4.y, a4.z, a4.w};
            float b[4] = {b4.x, b4.y, b4.z, b4.w};
#pragma unroll
            for (int i = 0; i < 4; i++)
#pragma unroll
                for (int j = 0; j < 4; j++)
                    acc[i][j] = fmaf(a[i], b[j], acc[i][j]);
        }
    }
    float bv[4];
#pragma unroll
    for (int j = 0; j < 4; j++) bv[j] = bias[n0 + (tx << 2) + j];
#pragma unroll
    for (int i = 0; i < 4; i++) {
        size_t off = (size_t)(m0 + (ty << 2) + i) * N + n0 + (tx << 2);
        *(float4*)(C + off) =
            make_float4(acc[i][0] + bv[0], acc[i][1] + bv[1],
                        acc[i][2] + bv[2], acc[i][3] + bv[3]);
    }
}

// ---------------------------------------------------------------------------
// 5) L2-normalize embed rows (in place) + ||e||^2. grid K/4, block 256 (1 wave/row)
__global__ __launch_bounds__(256) void k_l2norm(float* __restrict__ E, float* __restrict__ esq) {
    int tid = threadIdx.x;
    int row = blockIdx.x * 4 + (tid >> 6);
    int v = tid & 63;
    float x = E[((size_t)row << 6) + v];
    float ss = x * x;
#pragma unroll
    for (int off = 32; off; off >>= 1) ss += __shfl_xor(ss, off, 64);
    float inv = 1.f / (sqrtf(ss) + 1e-6f);
    E[((size_t)row << 6) + v] = x * inv;
    if (v == 0) esq[row] = ss * inv * inv;
}

// ---------------------------------------------------------------------------
// 6) projection: H[t,v] = sum_d h_in[b,d,t]*pw[v,d] + pb[v]   (raw, un-normalized)
// grid NT/64, block 256
__global__ __launch_bounds__(256) void k_proj(const float* __restrict__ h_in,
                                              const float* __restrict__ pw,
                                              const float* __restrict__ pb,
                                              float* __restrict__ H) {
    __shared__ float hs[16][64];
    __shared__ float wsh[16][68];
    int tid = threadIdx.x;
    int t0 = blockIdx.x * 64;
    int b = t0 >> 11;
    int tloc0 = t0 & (TT_ - 1);
    int tt = tid & 63, vg = tid >> 6;
    float acc[16] = {};
    for (int d0 = 0; d0 < DD; d0 += 16) {
        {
            int dd = tid >> 4, tq = (tid & 15) << 2;
            float4 hv = *(const float4*)(h_in + (((size_t)(b * DD + d0 + dd)) << 11) + tloc0 + tq);
            hs[dd][tq + 0] = hv.x; hs[dd][tq + 1] = hv.y;
            hs[dd][tq + 2] = hv.z; hs[dd][tq + 3] = hv.w;
            int v = tid >> 2, dq = (tid & 3) << 2;
            float4 wv = *(const float4*)(pw + (size_t)v * DD + d0 + dq);
            wsh[dq + 0][v] = wv.x; wsh[dq + 1][v] = wv.y;
            wsh[dq + 2][v] = wv.z; wsh[dq + 3][v] = wv.w;
        }
        __syncthreads();
#pragma unroll
        for (int dd = 0; dd < 16; dd++) {
            float hval = hs[dd][tt];
#pragma unroll
            for (int u = 0; u < 4; u++) {
                float4 w4 = *(const float4*)&wsh[dd][(vg << 4) + (u << 2)];
                acc[u * 4 + 0] = fmaf(hval, w4.x, acc[u * 4 + 0]);
                acc[u * 4 + 1] = fmaf(hval, w4.y, acc[u * 4 + 1]);
                acc[u * 4 + 2] = fmaf(hval, w4.z, acc[u * 4 + 2]);
                acc[u * 4 + 3] = fmaf(hval, w4.w, acc[u * 4 + 3]);
            }
        }
        __syncthreads();
    }
#pragma unroll
    for (int u = 0; u < 4; u++) {
        int v = (vg << 4) + (u << 2);
        float4 o = make_float4(acc[u * 4 + 0] + pb[v + 0],
                               acc[u * 4 + 1] + pb[v + 1],
                               acc[u * 4 + 2] + pb[v + 2],
                               acc[u * 4 + 3] + pb[v + 3]);
        *(float4*)(H + ((size_t)(t0 + tt) << 6) + v) = o;
    }
}

// ---------------------------------------------------------------------------
// 7) score/argmax partials: s(t,k) = 2*hhat(t).ehat(k) - ||ehat(k)||^2
// grid (NT/512, 16 k-splits), block 256, 2 t's per thread, 256 k per block
__global__ __launch_bounds__(256, 2) void k_argmax(const float* __restrict__ H,
                                                   const float* __restrict__ E,
                                                   const float* __restrict__ esq,
                                                   float* __restrict__ ps,
                                                   int* __restrict__ pi) {
    __shared__ float es[128 * 64];
    __shared__ float eq[128];
    float4* es4 = (float4*)es;
    int tid = threadIdx.x;
    int k0 = blockIdx.y << 8;
    int ta = (blockIdx.x << 9) + tid;
    int tb = ta + 256;
    float4 ha[16], hb[16];
    const float4* Ha = (const float4*)(H + ((size_t)ta << 6));
    const float4* Hb = (const float4*)(H + ((size_t)tb << 6));
    float ssa = 0.f, ssb = 0.f;
#pragma unroll
    for (int u = 0; u < 16; u++) {
        ha[u] = Ha[u]; hb[u] = Hb[u];
        ssa += ha[u].x * ha[u].x + ha[u].y * ha[u].y + ha[u].z * ha[u].z + ha[u].w * ha[u].w;
        ssb += hb[u].x * hb[u].x + hb[u].y * hb[u].y + hb[u].z * hb[u].z + hb[u].w * hb[u].w;
    }
    float inva = 1.f / (sqrtf(ssa) + 1e-6f);
    float invb = 1.f / (sqrtf(ssb) + 1e-6f);
#pragma unroll
    for (int u = 0; u < 16; u++) {
        ha[u].x *= inva; ha[u].y *= inva; ha[u].z *= inva; ha[u].w *= inva;
        hb[u].x *= invb; hb[u].y *= invb; hb[u].z *= invb; hb[u].w *= invb;
    }
    float besta = -1e30f, bestb = -1e30f;
    int ia = k0, ib = k0;
    for (int sub = 0; sub < 2; sub++) {
        int kb = k0 + (sub << 7);
        const float4* Esrc = (const float4*)(E + ((size_t)kb << 6));
        __syncthreads();
        for (int i = tid; i < 128 * 16; i += 256) es4[i] = Esrc[i];
        if (tid < 128) eq[tid] = esq[kb + tid];
        __syncthreads();
        for (int kk = 0; kk < 128; kk++) {
            const float4* ek = (const float4*)(es + (kk << 6));
            float sa = 0.f, sb = 0.f;
#pragma unroll
            for (int u = 0; u < 16; u++) {
                float4 e = ek[u];
                sa += ha[u].x * e.x + ha[u].y * e.y + ha[u].z * e.z + ha[u].w * e.w;
                sb += hb[u].x * e.x + hb[u].y * e.y + hb[u].z * e.z + hb[u].w * e.w;
            }
            float q = eq[kk];
            sa = sa + sa - q;
            sb = sb + sb - q;
            if (sa > besta) { besta = sa; ia = kb + kk; }
            if (sb > bestb) { bestb = sb; ib = kb + kk; }
        }
    }
    ps[(size_t)ta * 16 + blockIdx.y] = besta;
    pi[(size_t)ta * 16 + blockIdx.y] = ia;
    ps[(size_t)tb * 16 + blockIdx.y] = bestb;
    pi[(size_t)tb * 16 + blockIdx.y] = ib;
}

// ---------------------------------------------------------------------------
// 8) merge partials -> code; write vq_code (fp32, masked); gather G = mask*embed[code]
// grid NT/256, block 256
__global__ __launch_bounds__(256) void k_merge(const float* __restrict__ ps,
                                               const int* __restrict__ pi,
                                               const int* __restrict__ mask,
                                               const float* __restrict__ E,
                                               float* __restrict__ G,
                                               float* __restrict__ outc) {
    __shared__ int codes[256];
    __shared__ int ms[256];
    int tid = threadIdx.x;
    int base = blockIdx.x << 8;
    int t = base + tid;
    float best = -1e30f; int bi = 0;
    for (int s = 0; s < 16; s++) {
        float v = ps[(size_t)t * 16 + s];
        int idx = pi[(size_t)t * 16 + s];
        if (v > best) { best = v; bi = idx; }
    }
    int m = mask[t];
    codes[tid] = bi;
    ms[tid] = m;
    outc[t] = m ? (float)bi : 0.0f;
    __syncthreads();
    for (int i = tid; i < 256 * 16; i += 256) {
        int r = i >> 4, u = i & 15;
        float4 e = ms[r] ? ((const float4*)(E + ((size_t)codes[r] << 6)))[u]
                         : make_float4(0.f, 0.f, 0.f, 0.f);
        ((float4*)(G + ((size_t)(base + r) << 6)))[u] = e;
    }
}

// ---------------------------------------------------------------------------
extern "C" void kernel_launch(void* const* d_in, const int* in_sizes, int n_in,
                              void* d_out, int out_size, void* d_ws, size_t ws_size,
                              hipStream_t stream) {
    const float* h_in   = (const float*)d_in[0];
    const int*   amask  = (const int*)d_in[1];
    const float* proj_w = (const float*)d_in[2];
    const float* proj_b = (const float*)d_in[3];
    const float* inv_w  = (const float*)d_in[4];
    const float* inv_b  = (const float*)d_in[5];
    const float* w_in   = (const float*)d_in[6];
    const float* b_in   = (const float*)d_in[7];
    const float* w_mid  = (const float*)d_in[8];
    const float* b_mid  = (const float*)d_in[9];
    const float* w_out  = (const float*)d_in[10];
    const float* b_out  = (const float*)d_in[11];
    const float* gamma  = (const float*)d_in[12];
    const float* beta   = (const float*)d_in[13];

    float* X0  = (float*)d_ws;                       // K*HID
    float* X1  = X0 + (size_t)KK * HID_;             // K*HID
    float* mv  = X1 + (size_t)KK * HID_;             // 2*HID
    float* Emb = mv + 2 * HID_;                      // K*VQ
    float* esq = Emb + (size_t)KK * VQ_;             // K
    // overlap region (X1 free after the MLP chain):
    float* Hbuf   = X1;                              // NT*VQ
    float* pscore = X1 + (size_t)NT * VQ_;           // NT*16
    int*   pidx   = (int*)(pscore + (size_t)NT * 16);// NT*16
    float* G      = (float*)(pidx + (size_t)NT * 16);// NT*VQ

    float* out_q = (float*)d_out;                    // NT*DD fp32
    float* out_c = out_q + (size_t)NT * DD;          // NT fp32

    // codebook MLP
    k_mlp_in<<<dim3(HID_ / 256, KK / 16), 256, 0, stream>>>(w_in, b_in, X0);
    k_bn_stats<<<HID_, 256, 0, stream>>>(X0, mv);
    k_bn_apply<<<KK * HID_ / 1024, 256, 0, stream>>>(X0, mv, gamma, beta);
    float* src = X0; float* dst = X1;
    for (int i = 0; i < NMID; i++) {
        k_gemm<<<dim3(KK / 64, HID_ / 64), 256, 0, stream>>>(
            src, w_mid + (size_t)i * HID_ * HID_, b_mid + (size_t)i * HID_, dst,
            KK, HID_, HID_);
        k_bn_stats<<<HID_, 256, 0, stream>>>(dst, mv);
        k_bn_apply<<<KK * HID_ / 1024, 256, 0, stream>>>(dst, mv,
            gamma + (size_t)(i + 1) * HID_, beta + (size_t)(i + 1) * HID_);
        float* tmp = src; src = dst; dst = tmp;
    }
    // src == X0 here (4 swaps)
    k_gemm<<<dim3(KK / 64, VQ_ / 64), 256, 0, stream>>>(
        src, w_out, b_out, Emb, KK, VQ_, HID_);
    k_l2norm<<<KK / 4, 256, 0, stream>>>(Emb, esq);

    // hidden-state path
    k_proj<<<NT / 64, 256, 0, stream>>>(h_in, proj_w, proj_b, Hbuf);
    k_argmax<<<dim3(NT / 512, 16), 256, 0, stream>>>(Hbuf, Emb, esq, pscore, pidx);
    k_merge<<<NT / 256, 256, 0, stream>>>(pscore, pidx, amask, Emb, G, out_c);
    k_gemm<<<dim3(NT / 64, DD / 64), 256, 0, stream>>>(
        G, inv_w, inv_b, out_q, NT, DD, VQ_);
}

// Round 4
// 642.330 us; speedup vs baseline: 1.6551x; 1.6551x over previous
//
#include <hip/hip_runtime.h>
#include <stddef.h>

// Problem constants
#define BB   8
#define TT_  2048
#define DD   768
#define VQ_  64
#define L2C  12
#define HID_ 1024
#define KK   4096
#define NMID 4
#define NT   (BB*TT_)         // 16384 positions

typedef _Float16 h8v __attribute__((ext_vector_type(8)));
typedef float    f4v __attribute__((ext_vector_type(4)));

#define LDA 40   // LDS row stride in fp16 units (32 + 8 pad -> 2-way bank alias = free)

// ---------------------------------------------------------------------------
// 1) bits @ mlp_w_in.T + b_in  ->  Y [K, HID]
__global__ __launch_bounds__(256) void k_mlp_in(const float* __restrict__ w_in,
                                                const float* __restrict__ b_in,
                                                float* __restrict__ X) {
    __shared__ float ws_[256 * 12];
    __shared__ float bs_[256];
    int tid = threadIdx.x;
    int h0  = blockIdx.x * 256;
    for (int i = tid; i < 256 * 12; i += 256) ws_[i] = w_in[h0 * 12 + i];
    bs_[tid] = b_in[h0 + tid];
    __syncthreads();
    float w[12];
#pragma unroll
    for (int l = 0; l < 12; l++) w[l] = ws_[tid * 12 + l];
    float bias = bs_[tid];
    int k0 = blockIdx.y * 16;
    for (int kk = 0; kk < 16; kk++) {
        int k = k0 + kk;
        float acc = bias;
#pragma unroll
        for (int l = 0; l < 12; l++)
            if ((k >> (11 - l)) & 1) acc += w[l];
        X[(size_t)k * HID_ + h0 + tid] = acc;
    }
}

// ---------------------------------------------------------------------------
// 2a) BN stats stage 1: 64 blocks, each reduces 64 rows x 1024 cols (coalesced)
__global__ __launch_bounds__(256) void k_bn_stats1(const float* __restrict__ Y,
                                                   float* __restrict__ part) {
    int b = blockIdx.x, t = threadIdx.x;
    const float* src = Y + ((size_t)b << 6) * HID_ + (t << 2);
    float sx = 0.f, sy = 0.f, sz = 0.f, sw = 0.f;
    float qx = 0.f, qy = 0.f, qz = 0.f, qw = 0.f;
    for (int r = 0; r < 64; r++) {
        float4 v = *(const float4*)(src + ((size_t)r << 10));
        sx += v.x; sy += v.y; sz += v.z; sw += v.w;
        qx += v.x * v.x; qy += v.y * v.y; qz += v.z * v.z; qw += v.w * v.w;
    }
    *(float4*)(part + ((size_t)b << 10) + (t << 2)) = make_float4(sx, sy, sz, sw);
    *(float4*)(part + 65536 + ((size_t)b << 10) + (t << 2)) = make_float4(qx, qy, qz, qw);
}

// 2b) BN stats stage 2: reduce 64 partials per column -> mean/var. grid 4 x 256
__global__ __launch_bounds__(256) void k_bn_stats2(const float* __restrict__ part,
                                                   float* __restrict__ mv) {
    int c = blockIdx.x * 256 + threadIdx.x;
    float s = 0.f, q = 0.f;
    for (int b = 0; b < 64; b++) {
        s += part[((size_t)b << 10) + c];
        q += part[65536 + ((size_t)b << 10) + c];
    }
    float m = s * (1.f / KK);
    float v = q * (1.f / KK) - m * m;
    mv[c] = m; mv[HID_ + c] = v;
}

// ---------------------------------------------------------------------------
// 3) BN apply + ReLU, emit fp16 hi/lo split pair. grid K*HID/1024, block 256
__global__ __launch_bounds__(256) void k_bn_apply_split(const float* __restrict__ Y,
                                                        const float* __restrict__ mv,
                                                        const float* __restrict__ gamma,
                                                        const float* __restrict__ beta,
                                                        _Float16* __restrict__ Xhi,
                                                        _Float16* __restrict__ Xlo) {
    int i = blockIdx.x * 256 + threadIdx.x;       // float4 index
    int c = (i << 2) & (HID_ - 1);
    float4 x = ((const float4*)Y)[i];
    float4 m = *(const float4*)(mv + c);
    float4 v = *(const float4*)(mv + HID_ + c);
    float4 g = *(const float4*)(gamma + c);
    float4 b = *(const float4*)(beta + c);
    float o[4];
    o[0] = fmaxf(0.f, (x.x - m.x) * (1.f / sqrtf(v.x + 1e-5f)) * g.x + b.x);
    o[1] = fmaxf(0.f, (x.y - m.y) * (1.f / sqrtf(v.y + 1e-5f)) * g.y + b.y);
    o[2] = fmaxf(0.f, (x.z - m.z) * (1.f / sqrtf(v.z + 1e-5f)) * g.z + b.z);
    o[3] = fmaxf(0.f, (x.w - m.w) * (1.f / sqrtf(v.w + 1e-5f)) * g.w + b.w);
    union { _Float16 h[4]; uint2 u; } uh, ul;
#pragma unroll
    for (int j = 0; j < 4; j++) {
        _Float16 h = (_Float16)o[j];
        uh.h[j] = h;
        ul.h[j] = (_Float16)(o[j] - (float)h);
    }
    *(uint2*)(Xhi + ((size_t)i << 2)) = uh.u;
    *(uint2*)(Xlo + ((size_t)i << 2)) = ul.u;
}

// ---------------------------------------------------------------------------
// 4) C[M,N] = (Ahi+Alo)[M,K] @ W[N,K]^T + bias[N], fp32-accurate via 3-term
//    fp16-split MFMA. Tile 128x64, BK=32, block 256 (4 waves, each 64x32).
__global__ __launch_bounds__(256) void k_gemm_mfma(const _Float16* __restrict__ Ahi,
                                                   const _Float16* __restrict__ Alo,
                                                   const float* __restrict__ W,
                                                   const float* __restrict__ bias,
                                                   float* __restrict__ C,
                                                   int M, int N, int Kd) {
    __shared__ _Float16 sAh[128 * LDA];
    __shared__ _Float16 sAl[128 * LDA];
    __shared__ _Float16 sWh[64 * LDA];
    __shared__ _Float16 sWl[64 * LDA];
    const int tid = threadIdx.x;
    const int m0 = blockIdx.x * 128, n0 = blockIdx.y * 64;
    const int wave = tid >> 6, lane = tid & 63;
    const int wm = (wave >> 1) << 6;      // 0 / 64
    const int wn = (wave & 1) << 5;       // 0 / 32
    const int l15 = lane & 15, quad = lane >> 4;

    const int ar = tid >> 1;              // 0..127
    const int ak = (tid & 1) << 4;        // 0 / 16 (fp16 units)
    const int wr = tid >> 2;              // 0..63
    const int wk = (tid & 3) << 3;        // 0,8,16,24

    f4v acc[4][2];
#pragma unroll
    for (int i = 0; i < 4; i++)
#pragma unroll
        for (int j = 0; j < 2; j++) acc[i][j] = (f4v){0.f, 0.f, 0.f, 0.f};

    const size_t abase = (size_t)(m0 + ar) * Kd + ak;
    const size_t wbase = (size_t)(n0 + wr) * Kd + wk;

    for (int k0 = 0; k0 < Kd; k0 += 32) {
        uint4 a0 = *(const uint4*)(Ahi + abase + k0);
        uint4 a1 = *(const uint4*)(Ahi + abase + k0 + 8);
        uint4 c0 = *(const uint4*)(Alo + abase + k0);
        uint4 c1 = *(const uint4*)(Alo + abase + k0 + 8);
        float4 w0 = *(const float4*)(W + wbase + k0);
        float4 w1 = *(const float4*)(W + wbase + k0 + 4);
        union { _Float16 h[8]; uint4 u; } wh, wl;
        float wf[8] = {w0.x, w0.y, w0.z, w0.w, w1.x, w1.y, w1.z, w1.w};
#pragma unroll
        for (int j = 0; j < 8; j++) {
            _Float16 h = (_Float16)wf[j];
            wh.h[j] = h;
            wl.h[j] = (_Float16)(wf[j] - (float)h);
        }
        __syncthreads();
        *(uint4*)(sAh + ar * LDA + ak)     = a0;
        *(uint4*)(sAh + ar * LDA + ak + 8) = a1;
        *(uint4*)(sAl + ar * LDA + ak)     = c0;
        *(uint4*)(sAl + ar * LDA + ak + 8) = c1;
        *(uint4*)(sWh + wr * LDA + wk) = wh.u;
        *(uint4*)(sWl + wr * LDA + wk) = wl.u;
        __syncthreads();

        h8v ah[4], alv[4], bh[2], bl[2];
#pragma unroll
        for (int i = 0; i < 4; i++) {
            ah[i]  = *(const h8v*)(sAh + (wm + (i << 4) + l15) * LDA + (quad << 3));
            alv[i] = *(const h8v*)(sAl + (wm + (i << 4) + l15) * LDA + (quad << 3));
        }
#pragma unroll
        for (int j = 0; j < 2; j++) {
            bh[j] = *(const h8v*)(sWh + (wn + (j << 4) + l15) * LDA + (quad << 3));
            bl[j] = *(const h8v*)(sWl + (wn + (j << 4) + l15) * LDA + (quad << 3));
        }
#pragma unroll
        for (int i = 0; i < 4; i++)
#pragma unroll
            for (int j = 0; j < 2; j++) {
                acc[i][j] = __builtin_amdgcn_mfma_f32_16x16x32_f16(ah[i],  bh[j], acc[i][j], 0, 0, 0);
                acc[i][j] = __builtin_amdgcn_mfma_f32_16x16x32_f16(ah[i],  bl[j], acc[i][j], 0, 0, 0);
                acc[i][j] = __builtin_amdgcn_mfma_f32_16x16x32_f16(alv[i], bh[j], acc[i][j], 0, 0, 0);
            }
    }
#pragma unroll
    for (int j = 0; j < 2; j++) {
        int col = n0 + wn + (j << 4) + l15;
        float bv = bias[col];
#pragma unroll
        for (int i = 0; i < 4; i++) {
            int row = m0 + wm + (i << 4) + (quad << 2);
#pragma unroll
            for (int r = 0; r < 4; r++)
                C[(size_t)(row + r) * N + col] = acc[i][j][r] + bv;
        }
    }
}

// ---------------------------------------------------------------------------
// 5) L2-normalize embed rows (in place) + ||e||^2. grid K/4, block 256
__global__ __launch_bounds__(256) void k_l2norm(float* __restrict__ E, float* __restrict__ esq) {
    int tid = threadIdx.x;
    int row = blockIdx.x * 4 + (tid >> 6);
    int v = tid & 63;
    float x = E[((size_t)row << 6) + v];
    float ss = x * x;
#pragma unroll
    for (int off = 32; off; off >>= 1) ss += __shfl_xor(ss, off, 64);
    float inv = 1.f / (sqrtf(ss) + 1e-6f);
    E[((size_t)row << 6) + v] = x * inv;
    if (v == 0) esq[row] = ss * inv * inv;
}

// ---------------------------------------------------------------------------
// 6) projection: H[t,v] = sum_d h_in[b,d,t]*pw[v,d] + pb[v]
__global__ __launch_bounds__(256) void k_proj(const float* __restrict__ h_in,
                                              const float* __restrict__ pw,
                                              const float* __restrict__ pb,
                                              float* __restrict__ H) {
    __shared__ float hs[16][64];
    __shared__ float wsh[16][68];
    int tid = threadIdx.x;
    int t0 = blockIdx.x * 64;
    int b = t0 >> 11;
    int tloc0 = t0 & (TT_ - 1);
    int tt = tid & 63, vg = tid >> 6;
    float acc[16] = {};
    for (int d0 = 0; d0 < DD; d0 += 16) {
        {
            int dd = tid >> 4, tq = (tid & 15) << 2;
            float4 hv = *(const float4*)(h_in + (((size_t)(b * DD + d0 + dd)) << 11) + tloc0 + tq);
            hs[dd][tq + 0] = hv.x; hs[dd][tq + 1] = hv.y;
            hs[dd][tq + 2] = hv.z; hs[dd][tq + 3] = hv.w;
            int v = tid >> 2, dq = (tid & 3) << 2;
            float4 wv = *(const float4*)(pw + (size_t)v * DD + d0 + dq);
            wsh[dq + 0][v] = wv.x; wsh[dq + 1][v] = wv.y;
            wsh[dq + 2][v] = wv.z; wsh[dq + 3][v] = wv.w;
        }
        __syncthreads();
#pragma unroll
        for (int dd = 0; dd < 16; dd++) {
            float hval = hs[dd][tt];
#pragma unroll
            for (int u = 0; u < 4; u++) {
                float4 w4 = *(const float4*)&wsh[dd][(vg << 4) + (u << 2)];
                acc[u * 4 + 0] = fmaf(hval, w4.x, acc[u * 4 + 0]);
                acc[u * 4 + 1] = fmaf(hval, w4.y, acc[u * 4 + 1]);
                acc[u * 4 + 2] = fmaf(hval, w4.z, acc[u * 4 + 2]);
                acc[u * 4 + 3] = fmaf(hval, w4.w, acc[u * 4 + 3]);
            }
        }
        __syncthreads();
    }
#pragma unroll
    for (int u = 0; u < 4; u++) {
        int v = (vg << 4) + (u << 2);
        float4 o = make_float4(acc[u * 4 + 0] + pb[v + 0],
                               acc[u * 4 + 1] + pb[v + 1],
                               acc[u * 4 + 2] + pb[v + 2],
                               acc[u * 4 + 3] + pb[v + 3]);
        *(float4*)(H + ((size_t)(t0 + tt) << 6) + v) = o;
    }
}

// ---------------------------------------------------------------------------
// 7) score/argmax partials: s(t,k) = 2*hhat(t).ehat(k) - ||ehat(k)||^2
__global__ __launch_bounds__(256, 2) void k_argmax(const float* __restrict__ H,
                                                   const float* __restrict__ E,
                                                   const float* __restrict__ esq,
                                                   float* __restrict__ ps,
                                                   int* __restrict__ pi) {
    __shared__ float es[128 * 64];
    __shared__ float eq[128];
    float4* es4 = (float4*)es;
    int tid = threadIdx.x;
    int k0 = blockIdx.y << 8;
    int ta = (blockIdx.x << 9) + tid;
    int tb = ta + 256;
    float4 ha[16], hb[16];
    const float4* Ha = (const float4*)(H + ((size_t)ta << 6));
    const float4* Hb = (const float4*)(H + ((size_t)tb << 6));
    float ssa = 0.f, ssb = 0.f;
#pragma unroll
    for (int u = 0; u < 16; u++) {
        ha[u] = Ha[u]; hb[u] = Hb[u];
        ssa += ha[u].x * ha[u].x + ha[u].y * ha[u].y + ha[u].z * ha[u].z + ha[u].w * ha[u].w;
        ssb += hb[u].x * hb[u].x + hb[u].y * hb[u].y + hb[u].z * hb[u].z + hb[u].w * hb[u].w;
    }
    float inva = 1.f / (sqrtf(ssa) + 1e-6f);
    float invb = 1.f / (sqrtf(ssb) + 1e-6f);
#pragma unroll
    for (int u = 0; u < 16; u++) {
        ha[u].x *= inva; ha[u].y *= inva; ha[u].z *= inva; ha[u].w *= inva;
        hb[u].x *= invb; hb[u].y *= invb; hb[u].z *= invb; hb[u].w *= invb;
    }
    float besta = -1e30f, bestb = -1e30f;
    int ia = k0, ib = k0;
    for (int sub = 0; sub < 2; sub++) {
        int kb = k0 + (sub << 7);
        const float4* Esrc = (const float4*)(E + ((size_t)kb << 6));
        __syncthreads();
        for (int i = tid; i < 128 * 16; i += 256) es4[i] = Esrc[i];
        if (tid < 128) eq[tid] = esq[kb + tid];
        __syncthreads();
        for (int kk = 0; kk < 128; kk++) {
            const float4* ek = (const float4*)(es + (kk << 6));
            float sa = 0.f, sb = 0.f;
#pragma unroll
            for (int u = 0; u < 16; u++) {
                float4 e = ek[u];
                sa += ha[u].x * e.x + ha[u].y * e.y + ha[u].z * e.z + ha[u].w * e.w;
                sb += hb[u].x * e.x + hb[u].y * e.y + hb[u].z * e.z + hb[u].w * e.w;
            }
            float q = eq[kk];
            sa = sa + sa - q;
            sb = sb + sb - q;
            if (sa > besta) { besta = sa; ia = kb + kk; }
            if (sb > bestb) { bestb = sb; ib = kb + kk; }
        }
    }
    ps[(size_t)ta * 16 + blockIdx.y] = besta;
    pi[(size_t)ta * 16 + blockIdx.y] = ia;
    ps[(size_t)tb * 16 + blockIdx.y] = bestb;
    pi[(size_t)tb * 16 + blockIdx.y] = ib;
}

// ---------------------------------------------------------------------------
// 8) merge partials -> code; write vq_code (fp32, masked); gather G
__global__ __launch_bounds__(256) void k_merge(const float* __restrict__ ps,
                                               const int* __restrict__ pi,
                                               const int* __restrict__ mask,
                                               const float* __restrict__ E,
                                               float* __restrict__ G,
                                               float* __restrict__ outc) {
    __shared__ int codes[256];
    __shared__ int ms[256];
    int tid = threadIdx.x;
    int base = blockIdx.x << 8;
    int t = base + tid;
    float best = -1e30f; int bi = 0;
    for (int s = 0; s < 16; s++) {
        float v = ps[(size_t)t * 16 + s];
        int idx = pi[(size_t)t * 16 + s];
        if (v > best) { best = v; bi = idx; }
    }
    int m = mask[t];
    codes[tid] = bi;
    ms[tid] = m;
    outc[t] = m ? (float)bi : 0.0f;
    __syncthreads();
    for (int i = tid; i < 256 * 16; i += 256) {
        int r = i >> 4, u = i & 15;
        float4 e = ms[r] ? ((const float4*)(E + ((size_t)codes[r] << 6)))[u]
                         : make_float4(0.f, 0.f, 0.f, 0.f);
        ((float4*)(G + ((size_t)(base + r) << 6)))[u] = e;
    }
}

// ---------------------------------------------------------------------------
// 9) fp32 VALU GEMM kept for the final quantized projection (not precision-critical
//    for argmax, but only 1.6 GF; optimize later if it shows in the profile)
__global__ __launch_bounds__(256) void k_gemm(const float* __restrict__ A,
                                              const float* __restrict__ W,
                                              const float* __restrict__ bias,
                                              float* __restrict__ C,
                                              int M, int N, int Kd) {
    __shared__ float As[16][68];
    __shared__ float Bs[16][68];
    int tid = threadIdx.x;
    int m0 = blockIdx.x * 64, n0 = blockIdx.y * 64;
    int lr = tid >> 2;
    int lk = (tid & 3) << 2;
    int tx = tid & 15, ty = tid >> 4;
    float acc[4][4] = {};
    for (int k0 = 0; k0 < Kd; k0 += 16) {
        float4 av = *(const float4*)(A + (size_t)(m0 + lr) * Kd + k0 + lk);
        float4 wv = *(const float4*)(W + (size_t)(n0 + lr) * Kd + k0 + lk);
        __syncthreads();
        As[lk + 0][lr] = av.x; As[lk + 1][lr] = av.y;
        As[lk + 2][lr] = av.z; As[lk + 3][lr] = av.w;
        Bs[lk + 0][lr] = wv.x; Bs[lk + 1][lr] = wv.y;
        Bs[lk + 2][lr] = wv.z; Bs[lk + 3][lr] = wv.w;
        __syncthreads();
#pragma unroll
        for (int k = 0; k < 16; k++) {
            const float4 a4 = *(const float4*)&As[k][ty << 2];
            const float4 b4 = *(const float4*)&Bs[k][tx << 2];
            float a[4] = {a4.x, a4.y, a4.z, a4.w};
            float b[4] = {b4.x, b4.y, b4.z, b4.w};
#pragma unroll
            for (int i = 0; i < 4; i++)
#pragma unroll
                for (int j = 0; j < 4; j++)
                    acc[i][j] = fmaf(a[i], b[j], acc[i][j]);
        }
    }
    float bv[4];
#pragma unroll
    for (int j = 0; j < 4; j++) bv[j] = bias[n0 + (tx << 2) + j];
#pragma unroll
    for (int i = 0; i < 4; i++) {
        size_t off = (size_t)(m0 + (ty << 2) + i) * N + n0 + (tx << 2);
        *(float4*)(C + off) =
            make_float4(acc[i][0] + bv[0], acc[i][1] + bv[1],
                        acc[i][2] + bv[2], acc[i][3] + bv[3]);
    }
}

// ---------------------------------------------------------------------------
extern "C" void kernel_launch(void* const* d_in, const int* in_sizes, int n_in,
                              void* d_out, int out_size, void* d_ws, size_t ws_size,
                              hipStream_t stream) {
    const float* h_in   = (const float*)d_in[0];
    const int*   amask  = (const int*)d_in[1];
    const float* proj_w = (const float*)d_in[2];
    const float* proj_b = (const float*)d_in[3];
    const float* inv_w  = (const float*)d_in[4];
    const float* inv_b  = (const float*)d_in[5];
    const float* w_in   = (const float*)d_in[6];
    const float* b_in   = (const float*)d_in[7];
    const float* w_mid  = (const float*)d_in[8];
    const float* b_mid  = (const float*)d_in[9];
    const float* w_out  = (const float*)d_in[10];
    const float* b_out  = (const float*)d_in[11];
    const float* gamma  = (const float*)d_in[12];
    const float* beta   = (const float*)d_in[13];

    float*     Y    = (float*)d_ws;                          // K*HID fp32 (GEMM out)
    _Float16*  Xhi  = (_Float16*)(Y + (size_t)KK * HID_);    // K*HID fp16
    _Float16*  Xlo  = Xhi + (size_t)KK * HID_;               // K*HID fp16
    float*     mv   = (float*)(Xlo + (size_t)KK * HID_);     // 2*HID
    float*     Emb  = mv + 2 * HID_;                         // K*VQ
    float*     esq  = Emb + (size_t)KK * VQ_;                // K
    float*     spart= esq + KK;                              // 2*64*1024 stats partials
    // t-path overlap (Xhi/Xlo dead after out-layer GEMM):
    float* Hbuf   = (float*)Xhi;                             // NT*VQ
    float* pscore = Hbuf + (size_t)NT * VQ_;                 // NT*16
    int*   pidx   = (int*)(pscore + (size_t)NT * 16);        // NT*16
    float* G      = (float*)(pidx + (size_t)NT * 16);        // NT*VQ

    float* out_q = (float*)d_out;                            // NT*DD fp32
    float* out_c = out_q + (size_t)NT * DD;                  // NT fp32

    // codebook MLP (fp16-split MFMA chain, fp32-equivalent precision)
    k_mlp_in<<<dim3(HID_ / 256, KK / 16), 256, 0, stream>>>(w_in, b_in, Y);
    k_bn_stats1<<<64, 256, 0, stream>>>(Y, spart);
    k_bn_stats2<<<4, 256, 0, stream>>>(spart, mv);
    k_bn_apply_split<<<KK * HID_ / 1024, 256, 0, stream>>>(Y, mv, gamma, beta, Xhi, Xlo);
    for (int i = 0; i < NMID; i++) {
        k_gemm_mfma<<<dim3(KK / 128, HID_ / 64), 256, 0, stream>>>(
            Xhi, Xlo, w_mid + (size_t)i * HID_ * HID_, b_mid + (size_t)i * HID_, Y,
            KK, HID_, HID_);
        k_bn_stats1<<<64, 256, 0, stream>>>(Y, spart);
        k_bn_stats2<<<4, 256, 0, stream>>>(spart, mv);
        k_bn_apply_split<<<KK * HID_ / 1024, 256, 0, stream>>>(Y, mv,
            gamma + (size_t)(i + 1) * HID_, beta + (size_t)(i + 1) * HID_, Xhi, Xlo);
    }
    k_gemm_mfma<<<dim3(KK / 128, VQ_ / 64), 256, 0, stream>>>(
        Xhi, Xlo, w_out, b_out, Emb, KK, VQ_, HID_);
    k_l2norm<<<KK / 4, 256, 0, stream>>>(Emb, esq);

    // hidden-state path
    k_proj<<<NT / 64, 256, 0, stream>>>(h_in, proj_w, proj_b, Hbuf);
    k_argmax<<<dim3(NT / 512, 16), 256, 0, stream>>>(Hbuf, Emb, esq, pscore, pidx);
    k_merge<<<NT / 256, 256, 0, stream>>>(pscore, pidx, amask, Emb, G, out_c);
    k_gemm<<<dim3(NT / 64, DD / 64), 256, 0, stream>>>(
        G, inv_w, inv_b, out_q, NT, DD, VQ_);
}

// Round 5
// 595.381 us; speedup vs baseline: 1.7856x; 1.0789x over previous
//
#include <hip/hip_runtime.h>
#include <stddef.h>

// Problem constants
#define BB   8
#define TT_  2048
#define DD   768
#define VQ_  64
#define L2C  12
#define HID_ 1024
#define KK   4096
#define NMID 4
#define NT   (BB*TT_)         // 16384 positions

typedef _Float16 h8v __attribute__((ext_vector_type(8)));
typedef float    f4v __attribute__((ext_vector_type(4)));

#define LDA 40   // LDS row stride in fp16 units (32 + 8 pad -> 2-way bank alias = free)

// ---------------------------------------------------------------------------
// 1) bits @ mlp_w_in.T + b_in  ->  Y [K, HID]
__global__ __launch_bounds__(256) void k_mlp_in(const float* __restrict__ w_in,
                                                const float* __restrict__ b_in,
                                                float* __restrict__ X) {
    __shared__ float ws_[256 * 12];
    __shared__ float bs_[256];
    int tid = threadIdx.x;
    int h0  = blockIdx.x * 256;
    for (int i = tid; i < 256 * 12; i += 256) ws_[i] = w_in[h0 * 12 + i];
    bs_[tid] = b_in[h0 + tid];
    __syncthreads();
    float w[12];
#pragma unroll
    for (int l = 0; l < 12; l++) w[l] = ws_[tid * 12 + l];
    float bias = bs_[tid];
    int k0 = blockIdx.y * 16;
    for (int kk = 0; kk < 16; kk++) {
        int k = k0 + kk;
        float acc = bias;
#pragma unroll
        for (int l = 0; l < 12; l++)
            if ((k >> (11 - l)) & 1) acc += w[l];
        X[(size_t)k * HID_ + h0 + tid] = acc;
    }
}

// ---------------------------------------------------------------------------
// 2a) BN stats stage 1: 64 blocks, each reduces 64 rows x 1024 cols (coalesced)
__global__ __launch_bounds__(256) void k_bn_stats1(const float* __restrict__ Y,
                                                   float* __restrict__ part) {
    int b = blockIdx.x, t = threadIdx.x;
    const float* src = Y + ((size_t)b << 6) * HID_ + (t << 2);
    float sx = 0.f, sy = 0.f, sz = 0.f, sw = 0.f;
    float qx = 0.f, qy = 0.f, qz = 0.f, qw = 0.f;
    for (int r = 0; r < 64; r++) {
        float4 v = *(const float4*)(src + ((size_t)r << 10));
        sx += v.x; sy += v.y; sz += v.z; sw += v.w;
        qx += v.x * v.x; qy += v.y * v.y; qz += v.z * v.z; qw += v.w * v.w;
    }
    *(float4*)(part + ((size_t)b << 10) + (t << 2)) = make_float4(sx, sy, sz, sw);
    *(float4*)(part + 65536 + ((size_t)b << 10) + (t << 2)) = make_float4(qx, qy, qz, qw);
}

// 2b) BN stats stage 2: reduce 64 partials per column -> mean/var. grid 4 x 256
__global__ __launch_bounds__(256) void k_bn_stats2(const float* __restrict__ part,
                                                   float* __restrict__ mv) {
    int c = blockIdx.x * 256 + threadIdx.x;
    float s = 0.f, q = 0.f;
    for (int b = 0; b < 64; b++) {
        s += part[((size_t)b << 10) + c];
        q += part[65536 + ((size_t)b << 10) + c];
    }
    float m = s * (1.f / KK);
    float v = q * (1.f / KK) - m * m;
    mv[c] = m; mv[HID_ + c] = v;
}

// ---------------------------------------------------------------------------
// 3) BN apply + ReLU, emit fp16 hi/lo split pair. grid K*HID/1024, block 256
__global__ __launch_bounds__(256) void k_bn_apply_split(const float* __restrict__ Y,
                                                        const float* __restrict__ mv,
                                                        const float* __restrict__ gamma,
                                                        const float* __restrict__ beta,
                                                        _Float16* __restrict__ Xhi,
                                                        _Float16* __restrict__ Xlo) {
    int i = blockIdx.x * 256 + threadIdx.x;       // float4 index
    int c = (i << 2) & (HID_ - 1);
    float4 x = ((const float4*)Y)[i];
    float4 m = *(const float4*)(mv + c);
    float4 v = *(const float4*)(mv + HID_ + c);
    float4 g = *(const float4*)(gamma + c);
    float4 b = *(const float4*)(beta + c);
    float o[4];
    o[0] = fmaxf(0.f, (x.x - m.x) * (1.f / sqrtf(v.x + 1e-5f)) * g.x + b.x);
    o[1] = fmaxf(0.f, (x.y - m.y) * (1.f / sqrtf(v.y + 1e-5f)) * g.y + b.y);
    o[2] = fmaxf(0.f, (x.z - m.z) * (1.f / sqrtf(v.z + 1e-5f)) * g.z + b.z);
    o[3] = fmaxf(0.f, (x.w - m.w) * (1.f / sqrtf(v.w + 1e-5f)) * g.w + b.w);
    union { _Float16 h[4]; uint2 u; } uh, ul;
#pragma unroll
    for (int j = 0; j < 4; j++) {
        _Float16 h = (_Float16)o[j];
        uh.h[j] = h;
        ul.h[j] = (_Float16)(o[j] - (float)h);
    }
    *(uint2*)(Xhi + ((size_t)i << 2)) = uh.u;
    *(uint2*)(Xlo + ((size_t)i << 2)) = ul.u;
}

// ---------------------------------------------------------------------------
// 4) C[M,N] = (Ahi+Alo)[M,K] @ W[N,K]^T + bias[N], fp32-accurate via 3-term
//    fp16-split MFMA. Tile 128x64, BK=32, block 256 (4 waves, each 64x32).
__global__ __launch_bounds__(256) void k_gemm_mfma(const _Float16* __restrict__ Ahi,
                                                   const _Float16* __restrict__ Alo,
                                                   const float* __restrict__ W,
                                                   const float* __restrict__ bias,
                                                   float* __restrict__ C,
                                                   int M, int N, int Kd) {
    __shared__ _Float16 sAh[128 * LDA];
    __shared__ _Float16 sAl[128 * LDA];
    __shared__ _Float16 sWh[64 * LDA];
    __shared__ _Float16 sWl[64 * LDA];
    const int tid = threadIdx.x;
    const int m0 = blockIdx.x * 128, n0 = blockIdx.y * 64;
    const int wave = tid >> 6, lane = tid & 63;
    const int wm = (wave >> 1) << 6;      // 0 / 64
    const int wn = (wave & 1) << 5;       // 0 / 32
    const int l15 = lane & 15, quad = lane >> 4;

    const int ar = tid >> 1;              // 0..127
    const int ak = (tid & 1) << 4;        // 0 / 16 (fp16 units)
    const int wr = tid >> 2;              // 0..63
    const int wk = (tid & 3) << 3;        // 0,8,16,24

    f4v acc[4][2];
#pragma unroll
    for (int i = 0; i < 4; i++)
#pragma unroll
        for (int j = 0; j < 2; j++) acc[i][j] = (f4v){0.f, 0.f, 0.f, 0.f};

    const size_t abase = (size_t)(m0 + ar) * Kd + ak;
    const size_t wbase = (size_t)(n0 + wr) * Kd + wk;

    for (int k0 = 0; k0 < Kd; k0 += 32) {
        uint4 a0 = *(const uint4*)(Ahi + abase + k0);
        uint4 a1 = *(const uint4*)(Ahi + abase + k0 + 8);
        uint4 c0 = *(const uint4*)(Alo + abase + k0);
        uint4 c1 = *(const uint4*)(Alo + abase + k0 + 8);
        float4 w0 = *(const float4*)(W + wbase + k0);
        float4 w1 = *(const float4*)(W + wbase + k0 + 4);
        union { _Float16 h[8]; uint4 u; } wh, wl;
        float wf[8] = {w0.x, w0.y, w0.z, w0.w, w1.x, w1.y, w1.z, w1.w};
#pragma unroll
        for (int j = 0; j < 8; j++) {
            _Float16 h = (_Float16)wf[j];
            wh.h[j] = h;
            wl.h[j] = (_Float16)(wf[j] - (float)h);
        }
        __syncthreads();
        *(uint4*)(sAh + ar * LDA + ak)     = a0;
        *(uint4*)(sAh + ar * LDA + ak + 8) = a1;
        *(uint4*)(sAl + ar * LDA + ak)     = c0;
        *(uint4*)(sAl + ar * LDA + ak + 8) = c1;
        *(uint4*)(sWh + wr * LDA + wk) = wh.u;
        *(uint4*)(sWl + wr * LDA + wk) = wl.u;
        __syncthreads();

        h8v ah[4], alv[4], bh[2], bl[2];
#pragma unroll
        for (int i = 0; i < 4; i++) {
            ah[i]  = *(const h8v*)(sAh + (wm + (i << 4) + l15) * LDA + (quad << 3));
            alv[i] = *(const h8v*)(sAl + (wm + (i << 4) + l15) * LDA + (quad << 3));
        }
#pragma unroll
        for (int j = 0; j < 2; j++) {
            bh[j] = *(const h8v*)(sWh + (wn + (j << 4) + l15) * LDA + (quad << 3));
            bl[j] = *(const h8v*)(sWl + (wn + (j << 4) + l15) * LDA + (quad << 3));
        }
#pragma unroll
        for (int i = 0; i < 4; i++)
#pragma unroll
            for (int j = 0; j < 2; j++) {
                acc[i][j] = __builtin_amdgcn_mfma_f32_16x16x32_f16(ah[i],  bh[j], acc[i][j], 0, 0, 0);
                acc[i][j] = __builtin_amdgcn_mfma_f32_16x16x32_f16(ah[i],  bl[j], acc[i][j], 0, 0, 0);
                acc[i][j] = __builtin_amdgcn_mfma_f32_16x16x32_f16(alv[i], bh[j], acc[i][j], 0, 0, 0);
            }
    }
#pragma unroll
    for (int j = 0; j < 2; j++) {
        int col = n0 + wn + (j << 4) + l15;
        float bv = bias[col];
#pragma unroll
        for (int i = 0; i < 4; i++) {
            int row = m0 + wm + (i << 4) + (quad << 2);
#pragma unroll
            for (int r = 0; r < 4; r++)
                C[(size_t)(row + r) * N + col] = acc[i][j][r] + bv;
        }
    }
}

// ---------------------------------------------------------------------------
// 5) L2-normalize embed rows (in place) + f16 split + eqh = -0.5*||ehat||^2
__global__ __launch_bounds__(256) void k_l2norm(float* __restrict__ E,
                                                float* __restrict__ eqh,
                                                _Float16* __restrict__ Ehi,
                                                _Float16* __restrict__ Elo) {
    int tid = threadIdx.x;
    int row = blockIdx.x * 4 + (tid >> 6);
    int v = tid & 63;
    size_t off = ((size_t)row << 6) + v;
    float x = E[off];
    float ss = x * x;
#pragma unroll
    for (int o = 32; o; o >>= 1) ss += __shfl_xor(ss, o, 64);
    float inv = 1.f / (sqrtf(ss) + 1e-6f);
    float xn = x * inv;
    E[off] = xn;
    _Float16 hh = (_Float16)xn;
    Ehi[off] = hh;
    Elo[off] = (_Float16)(xn - (float)hh);
    if (v == 0) eqh[row] = -0.5f * (ss * inv * inv);
}

// ---------------------------------------------------------------------------
// 6) projection + row L2-norm + f16 hi/lo split: Hhat[t][64]
// grid NT/64, block 256
__global__ __launch_bounds__(256) void k_proj(const float* __restrict__ h_in,
                                              const float* __restrict__ pw,
                                              const float* __restrict__ pb,
                                              _Float16* __restrict__ Hhi,
                                              _Float16* __restrict__ Hlo) {
    __shared__ float hs[16][64];
    __shared__ float wsh[16][68];
    __shared__ float ssp[4][64];
    int tid = threadIdx.x;
    int t0 = blockIdx.x * 64;
    int b = t0 >> 11;
    int tloc0 = t0 & (TT_ - 1);
    int tt = tid & 63, vg = tid >> 6;
    float acc[16] = {};
    for (int d0 = 0; d0 < DD; d0 += 16) {
        {
            int dd = tid >> 4, tq = (tid & 15) << 2;
            float4 hv = *(const float4*)(h_in + (((size_t)(b * DD + d0 + dd)) << 11) + tloc0 + tq);
            hs[dd][tq + 0] = hv.x; hs[dd][tq + 1] = hv.y;
            hs[dd][tq + 2] = hv.z; hs[dd][tq + 3] = hv.w;
            int v = tid >> 2, dq = (tid & 3) << 2;
            float4 wv = *(const float4*)(pw + (size_t)v * DD + d0 + dq);
            wsh[dq + 0][v] = wv.x; wsh[dq + 1][v] = wv.y;
            wsh[dq + 2][v] = wv.z; wsh[dq + 3][v] = wv.w;
        }
        __syncthreads();
#pragma unroll
        for (int dd = 0; dd < 16; dd++) {
            float hval = hs[dd][tt];
#pragma unroll
            for (int u = 0; u < 4; u++) {
                float4 w4 = *(const float4*)&wsh[dd][(vg << 4) + (u << 2)];
                acc[u * 4 + 0] = fmaf(hval, w4.x, acc[u * 4 + 0]);
                acc[u * 4 + 1] = fmaf(hval, w4.y, acc[u * 4 + 1]);
                acc[u * 4 + 2] = fmaf(hval, w4.z, acc[u * 4 + 2]);
                acc[u * 4 + 3] = fmaf(hval, w4.w, acc[u * 4 + 3]);
            }
        }
        __syncthreads();
    }
    float o[16];
    float sp = 0.f;
#pragma unroll
    for (int j = 0; j < 16; j++) {
        o[j] = acc[j] + pb[(vg << 4) + j];
        sp = fmaf(o[j], o[j], sp);
    }
    ssp[vg][tt] = sp;
    __syncthreads();
    float ss = ssp[0][tt] + ssp[1][tt] + ssp[2][tt] + ssp[3][tt];
    float inv = 1.f / (sqrtf(ss) + 1e-6f);
    union { _Float16 h[8]; uint4 u; } uh0, uh1, ul0, ul1;
#pragma unroll
    for (int j = 0; j < 16; j++) {
        float xn = o[j] * inv;
        _Float16 hh = (_Float16)xn;
        _Float16 ll = (_Float16)(xn - (float)hh);
        if (j < 8) { uh0.h[j] = hh; ul0.h[j] = ll; }
        else       { uh1.h[j - 8] = hh; ul1.h[j - 8] = ll; }
    }
    size_t hb = ((size_t)(t0 + tt) << 6) + (vg << 4);
    *(uint4*)(Hhi + hb)     = uh0.u;
    *(uint4*)(Hhi + hb + 8) = uh1.u;
    *(uint4*)(Hlo + hb)     = ul0.u;
    *(uint4*)(Hlo + hb + 8) = ul1.u;
}

// ---------------------------------------------------------------------------
// 7) MFMA argmax: s'(t,k) = hhat.ehat - 0.5*||ehat||^2, argmax over k.
// A = Ehat (k-side), B = Hhat (t-side); C: col(lane&15)=t, row(quad*4+r)=k.
// grid (NT/256, 4 k-splits), block 256. Each wave: 4 t-tiles of 16, k-range 1024.
__global__ __launch_bounds__(256) void k_argmax_mfma(const _Float16* __restrict__ Hhi,
                                                     const _Float16* __restrict__ Hlo,
                                                     const _Float16* __restrict__ Ehi,
                                                     const _Float16* __restrict__ Elo,
                                                     const float* __restrict__ eqh,
                                                     float* __restrict__ ps,
                                                     int* __restrict__ pi) {
    int tid = threadIdx.x;
    int wave = tid >> 6, lane = tid & 63;
    int l15 = lane & 15, quad = lane >> 4;
    int t0 = blockIdx.x * 256 + wave * 64;
    int kh = blockIdx.y;                  // 0..3, k-range [kh*1024, kh*1024+1024)

    h8v hh0[4], hh1[4], hl0[4], hl1[4];
#pragma unroll
    for (int s = 0; s < 4; s++) {
        size_t hb = (size_t)(t0 + (s << 4) + l15) * 64 + (quad << 3);
        hh0[s] = *(const h8v*)(Hhi + hb);
        hh1[s] = *(const h8v*)(Hhi + hb + 32);
        hl0[s] = *(const h8v*)(Hlo + hb);
        hl1[s] = *(const h8v*)(Hlo + hb + 32);
    }
    float best[4] = {-1e30f, -1e30f, -1e30f, -1e30f};
    int   idx[4]  = {0, 0, 0, 0};

    for (int it = 0; it < 64; it++) {
        int k0 = (kh << 10) + (it << 4);
        size_t eb = (size_t)(k0 + l15) * 64 + (quad << 3);
        h8v eh0 = *(const h8v*)(Ehi + eb);
        h8v eh1 = *(const h8v*)(Ehi + eb + 32);
        h8v el0 = *(const h8v*)(Elo + eb);
        h8v el1 = *(const h8v*)(Elo + eb + 32);
        float4 q4 = *(const float4*)(eqh + k0 + (quad << 2));
        f4v acc[4];
#pragma unroll
        for (int s = 0; s < 4; s++) acc[s] = (f4v){0.f, 0.f, 0.f, 0.f};
#pragma unroll
        for (int s = 0; s < 4; s++) acc[s] = __builtin_amdgcn_mfma_f32_16x16x32_f16(eh0, hh0[s], acc[s], 0, 0, 0);
#pragma unroll
        for (int s = 0; s < 4; s++) acc[s] = __builtin_amdgcn_mfma_f32_16x16x32_f16(eh1, hh1[s], acc[s], 0, 0, 0);
#pragma unroll
        for (int s = 0; s < 4; s++) acc[s] = __builtin_amdgcn_mfma_f32_16x16x32_f16(el0, hh0[s], acc[s], 0, 0, 0);
#pragma unroll
        for (int s = 0; s < 4; s++) acc[s] = __builtin_amdgcn_mfma_f32_16x16x32_f16(el1, hh1[s], acc[s], 0, 0, 0);
#pragma unroll
        for (int s = 0; s < 4; s++) acc[s] = __builtin_amdgcn_mfma_f32_16x16x32_f16(eh0, hl0[s], acc[s], 0, 0, 0);
#pragma unroll
        for (int s = 0; s < 4; s++) acc[s] = __builtin_amdgcn_mfma_f32_16x16x32_f16(eh1, hl1[s], acc[s], 0, 0, 0);
        float qv[4] = {q4.x, q4.y, q4.z, q4.w};
#pragma unroll
        for (int r = 0; r < 4; r++) {
            int k = k0 + (quad << 2) + r;
#pragma unroll
            for (int s = 0; s < 4; s++) {
                float sc = acc[s][r] + qv[r];
                if (sc > best[s]) { best[s] = sc; idx[s] = k; }
            }
        }
    }
    // cross-quad reduce: lanes l, l^16, l^32 share the same t (same lane&15)
#pragma unroll
    for (int m = 16; m <= 32; m <<= 1) {
#pragma unroll
        for (int s = 0; s < 4; s++) {
            float ob = __shfl_xor(best[s], m, 64);
            int   oi = __shfl_xor(idx[s], m, 64);
            if (ob > best[s] || (ob == best[s] && oi < idx[s])) { best[s] = ob; idx[s] = oi; }
        }
    }
    if (quad == 0) {
#pragma unroll
        for (int s = 0; s < 4; s++) {
            int t = t0 + (s << 4) + l15;
            ps[(size_t)t * 4 + kh] = best[s];
            pi[(size_t)t * 4 + kh] = idx[s];
        }
    }
}

// ---------------------------------------------------------------------------
// 8) merge 4 partials -> code; write vq_code (fp32, masked); gather G
__global__ __launch_bounds__(256) void k_merge(const float* __restrict__ ps,
                                               const int* __restrict__ pi,
                                               const int* __restrict__ mask,
                                               const float* __restrict__ E,
                                               float* __restrict__ G,
                                               float* __restrict__ outc) {
    __shared__ int codes[256];
    __shared__ int ms[256];
    int tid = threadIdx.x;
    int base = blockIdx.x << 8;
    int t = base + tid;
    float best = ps[(size_t)t * 4];
    int bi = pi[(size_t)t * 4];
#pragma unroll
    for (int s = 1; s < 4; s++) {
        float v = ps[(size_t)t * 4 + s];
        if (v > best) { best = v; bi = pi[(size_t)t * 4 + s]; }
    }
    int m = mask[t];
    codes[tid] = bi;
    ms[tid] = m;
    outc[t] = m ? (float)bi : 0.0f;
    __syncthreads();
    for (int i = tid; i < 256 * 16; i += 256) {
        int r = i >> 4, u = i & 15;
        float4 e = ms[r] ? ((const float4*)(E + ((size_t)codes[r] << 6)))[u]
                         : make_float4(0.f, 0.f, 0.f, 0.f);
        ((float4*)(G + ((size_t)(base + r) << 6)))[u] = e;
    }
}

// ---------------------------------------------------------------------------
// 9) fp32 VALU GEMM for the final quantized projection
__global__ __launch_bounds__(256) void k_gemm(const float* __restrict__ A,
                                              const float* __restrict__ W,
                                              const float* __restrict__ bias,
                                              float* __restrict__ C,
                                              int M, int N, int Kd) {
    __shared__ float As[16][68];
    __shared__ float Bs[16][68];
    int tid = threadIdx.x;
    int m0 = blockIdx.x * 64, n0 = blockIdx.y * 64;
    int lr = tid >> 2;
    int lk = (tid & 3) << 2;
    int tx = tid & 15, ty = tid >> 4;
    float acc[4][4] = {};
    for (int k0 = 0; k0 < Kd; k0 += 16) {
        float4 av = *(const float4*)(A + (size_t)(m0 + lr) * Kd + k0 + lk);
        float4 wv = *(const float4*)(W + (size_t)(n0 + lr) * Kd + k0 + lk);
        __syncthreads();
        As[lk + 0][lr] = av.x; As[lk + 1][lr] = av.y;
        As[lk + 2][lr] = av.z; As[lk + 3][lr] = av.w;
        Bs[lk + 0][lr] = wv.x; Bs[lk + 1][lr] = wv.y;
        Bs[lk + 2][lr] = wv.z; Bs[lk + 3][lr] = wv.w;
        __syncthreads();
#pragma unroll
        for (int k = 0; k < 16; k++) {
            const float4 a4 = *(const float4*)&As[k][ty << 2];
            const float4 b4 = *(const float4*)&Bs[k][tx << 2];
            float a[4] = {a4.x, a4.y, a4.z, a4.w};
            float b[4] = {b4.x, b4.y, b4.z, b4.w};
#pragma unroll
            for (int i = 0; i < 4; i++)
#pragma unroll
                for (int j = 0; j < 4; j++)
                    acc[i][j] = fmaf(a[i], b[j], acc[i][j]);
        }
    }
    float bv[4];
#pragma unroll
    for (int j = 0; j < 4; j++) bv[j] = bias[n0 + (tx << 2) + j];
#pragma unroll
    for (int i = 0; i < 4; i++) {
        size_t off = (size_t)(m0 + (ty << 2) + i) * N + n0 + (tx << 2);
        *(float4*)(C + off) =
            make_float4(acc[i][0] + bv[0], acc[i][1] + bv[1],
                        acc[i][2] + bv[2], acc[i][3] + bv[3]);
    }
}

// ---------------------------------------------------------------------------
extern "C" void kernel_launch(void* const* d_in, const int* in_sizes, int n_in,
                              void* d_out, int out_size, void* d_ws, size_t ws_size,
                              hipStream_t stream) {
    const float* h_in   = (const float*)d_in[0];
    const int*   amask  = (const int*)d_in[1];
    const float* proj_w = (const float*)d_in[2];
    const float* proj_b = (const float*)d_in[3];
    const float* inv_w  = (const float*)d_in[4];
    const float* inv_b  = (const float*)d_in[5];
    const float* w_in   = (const float*)d_in[6];
    const float* b_in   = (const float*)d_in[7];
    const float* w_mid  = (const float*)d_in[8];
    const float* b_mid  = (const float*)d_in[9];
    const float* w_out  = (const float*)d_in[10];
    const float* b_out  = (const float*)d_in[11];
    const float* gamma  = (const float*)d_in[12];
    const float* beta   = (const float*)d_in[13];

    float*     Y    = (float*)d_ws;                          // K*HID fp32
    _Float16*  Xhi  = (_Float16*)(Y + (size_t)KK * HID_);    // K*HID fp16
    _Float16*  Xlo  = Xhi + (size_t)KK * HID_;               // K*HID fp16
    float*     mv   = (float*)(Xlo + (size_t)KK * HID_);     // 2*HID
    float*     Emb  = mv + 2 * HID_;                         // K*VQ fp32
    float*     eqh  = Emb + (size_t)KK * VQ_;                // K
    float*     spart= eqh + KK;                              // 2*64*1024 stats partials
    // t-path overlay (Xhi/Xlo region free after out-layer GEMM):
    _Float16* H16hi = Xhi;                                   // NT*64 f16
    _Float16* H16lo = H16hi + (size_t)NT * VQ_;              // NT*64 f16
    _Float16* E16hi = H16lo + (size_t)NT * VQ_;              // K*64 f16
    _Float16* E16lo = E16hi + (size_t)KK * VQ_;              // K*64 f16
    float*    ps    = (float*)(E16lo + (size_t)KK * VQ_);    // NT*4
    int*      pidx  = (int*)(ps + (size_t)NT * 4);           // NT*4
    float*    G     = (float*)(pidx + (size_t)NT * 4);       // NT*64 fp32

    float* out_q = (float*)d_out;                            // NT*DD fp32
    float* out_c = out_q + (size_t)NT * DD;                  // NT fp32

    // codebook MLP (fp16-split MFMA chain, fp32-equivalent precision)
    k_mlp_in<<<dim3(HID_ / 256, KK / 16), 256, 0, stream>>>(w_in, b_in, Y);
    k_bn_stats1<<<64, 256, 0, stream>>>(Y, spart);
    k_bn_stats2<<<4, 256, 0, stream>>>(spart, mv);
    k_bn_apply_split<<<KK * HID_ / 1024, 256, 0, stream>>>(Y, mv, gamma, beta, Xhi, Xlo);
    for (int i = 0; i < NMID; i++) {
        k_gemm_mfma<<<dim3(KK / 128, HID_ / 64), 256, 0, stream>>>(
            Xhi, Xlo, w_mid + (size_t)i * HID_ * HID_, b_mid + (size_t)i * HID_, Y,
            KK, HID_, HID_);
        k_bn_stats1<<<64, 256, 0, stream>>>(Y, spart);
        k_bn_stats2<<<4, 256, 0, stream>>>(spart, mv);
        k_bn_apply_split<<<KK * HID_ / 1024, 256, 0, stream>>>(Y, mv,
            gamma + (size_t)(i + 1) * HID_, beta + (size_t)(i + 1) * HID_, Xhi, Xlo);
    }
    k_gemm_mfma<<<dim3(KK / 128, VQ_ / 64), 256, 0, stream>>>(
        Xhi, Xlo, w_out, b_out, Emb, KK, VQ_, HID_);
    k_l2norm<<<KK / 4, 256, 0, stream>>>(Emb, eqh, E16hi, E16lo);

    // hidden-state path
    k_proj<<<NT / 64, 256, 0, stream>>>(h_in, proj_w, proj_b, H16hi, H16lo);
    k_argmax_mfma<<<dim3(NT / 256, 4), 256, 0, stream>>>(
        H16hi, H16lo, E16hi, E16lo, eqh, ps, pidx);
    k_merge<<<NT / 256, 256, 0, stream>>>(ps, pidx, amask, Emb, G, out_c);
    k_gemm<<<dim3(NT / 64, DD / 64), 256, 0, stream>>>(
        G, inv_w, inv_b, out_q, NT, DD, VQ_);
}

// Round 6
// 554.662 us; speedup vs baseline: 1.9167x; 1.0734x over previous
//
#include <hip/hip_runtime.h>
#include <stddef.h>

// Problem constants
#define BB   8
#define TT_  2048
#define DD   768
#define VQ_  64
#define L2C  12
#define HID_ 1024
#define KK   4096
#define NMID 4
#define NT   (BB*TT_)         // 16384 positions

typedef _Float16 h8v __attribute__((ext_vector_type(8)));
typedef float    f4v __attribute__((ext_vector_type(4)));

#define LDA 40   // LDS row stride in fp16 units (32 + 8 pad -> 2-way bank alias = free)

// ---------------------------------------------------------------------------
// 1) bits @ mlp_w_in.T + b_in  ->  Y [K, HID]
__global__ __launch_bounds__(256) void k_mlp_in(const float* __restrict__ w_in,
                                                const float* __restrict__ b_in,
                                                float* __restrict__ X) {
    __shared__ float ws_[256 * 12];
    __shared__ float bs_[256];
    int tid = threadIdx.x;
    int h0  = blockIdx.x * 256;
    for (int i = tid; i < 256 * 12; i += 256) ws_[i] = w_in[h0 * 12 + i];
    bs_[tid] = b_in[h0 + tid];
    __syncthreads();
    float w[12];
#pragma unroll
    for (int l = 0; l < 12; l++) w[l] = ws_[tid * 12 + l];
    float bias = bs_[tid];
    int k0 = blockIdx.y * 16;
    for (int kk = 0; kk < 16; kk++) {
        int k = k0 + kk;
        float acc = bias;
#pragma unroll
        for (int l = 0; l < 12; l++)
            if ((k >> (11 - l)) & 1) acc += w[l];
        X[(size_t)k * HID_ + h0 + tid] = acc;
    }
}

// ---------------------------------------------------------------------------
// 2a) BN stats stage 1: 64 blocks, each reduces 64 rows x 1024 cols (coalesced)
__global__ __launch_bounds__(256) void k_bn_stats1(const float* __restrict__ Y,
                                                   float* __restrict__ part) {
    int b = blockIdx.x, t = threadIdx.x;
    const float* src = Y + ((size_t)b << 6) * HID_ + (t << 2);
    float sx = 0.f, sy = 0.f, sz = 0.f, sw = 0.f;
    float qx = 0.f, qy = 0.f, qz = 0.f, qw = 0.f;
    for (int r = 0; r < 64; r++) {
        float4 v = *(const float4*)(src + ((size_t)r << 10));
        sx += v.x; sy += v.y; sz += v.z; sw += v.w;
        qx += v.x * v.x; qy += v.y * v.y; qz += v.z * v.z; qw += v.w * v.w;
    }
    *(float4*)(part + ((size_t)b << 10) + (t << 2)) = make_float4(sx, sy, sz, sw);
    *(float4*)(part + 65536 + ((size_t)b << 10) + (t << 2)) = make_float4(qx, qy, qz, qw);
}

// 2b) BN stats stage 2: reduce 64 partials per column -> mean/var. grid 4 x 256
__global__ __launch_bounds__(256) void k_bn_stats2(const float* __restrict__ part,
                                                   float* __restrict__ mv) {
    int c = blockIdx.x * 256 + threadIdx.x;
    float s = 0.f, q = 0.f;
    for (int b = 0; b < 64; b++) {
        s += part[((size_t)b << 10) + c];
        q += part[65536 + ((size_t)b << 10) + c];
    }
    float m = s * (1.f / KK);
    float v = q * (1.f / KK) - m * m;
    mv[c] = m; mv[HID_ + c] = v;
}

// ---------------------------------------------------------------------------
// 3) BN apply + ReLU, emit fp16 hi/lo split pair. grid K*HID/1024, block 256
__global__ __launch_bounds__(256) void k_bn_apply_split(const float* __restrict__ Y,
                                                        const float* __restrict__ mv,
                                                        const float* __restrict__ gamma,
                                                        const float* __restrict__ beta,
                                                        _Float16* __restrict__ Xhi,
                                                        _Float16* __restrict__ Xlo) {
    int i = blockIdx.x * 256 + threadIdx.x;       // float4 index
    int c = (i << 2) & (HID_ - 1);
    float4 x = ((const float4*)Y)[i];
    float4 m = *(const float4*)(mv + c);
    float4 v = *(const float4*)(mv + HID_ + c);
    float4 g = *(const float4*)(gamma + c);
    float4 b = *(const float4*)(beta + c);
    float o[4];
    o[0] = fmaxf(0.f, (x.x - m.x) * (1.f / sqrtf(v.x + 1e-5f)) * g.x + b.x);
    o[1] = fmaxf(0.f, (x.y - m.y) * (1.f / sqrtf(v.y + 1e-5f)) * g.y + b.y);
    o[2] = fmaxf(0.f, (x.z - m.z) * (1.f / sqrtf(v.z + 1e-5f)) * g.z + b.z);
    o[3] = fmaxf(0.f, (x.w - m.w) * (1.f / sqrtf(v.w + 1e-5f)) * g.w + b.w);
    union { _Float16 h[4]; uint2 u; } uh, ul;
#pragma unroll
    for (int j = 0; j < 4; j++) {
        _Float16 h = (_Float16)o[j];
        uh.h[j] = h;
        ul.h[j] = (_Float16)(o[j] - (float)h);
    }
    *(uint2*)(Xhi + ((size_t)i << 2)) = uh.u;
    *(uint2*)(Xlo + ((size_t)i << 2)) = ul.u;
}

// ---------------------------------------------------------------------------
// 4) C[M,N] = (Ahi+Alo)[M,K] @ W[N,K]^T + bias[N], fp32-accurate via 3-term
//    fp16-split MFMA. Tile 128x64, BK=32, block 256 (4 waves, each 64x32).
__global__ __launch_bounds__(256) void k_gemm_mfma(const _Float16* __restrict__ Ahi,
                                                   const _Float16* __restrict__ Alo,
                                                   const float* __restrict__ W,
                                                   const float* __restrict__ bias,
                                                   float* __restrict__ C,
                                                   int M, int N, int Kd) {
    __shared__ _Float16 sAh[128 * LDA];
    __shared__ _Float16 sAl[128 * LDA];
    __shared__ _Float16 sWh[64 * LDA];
    __shared__ _Float16 sWl[64 * LDA];
    const int tid = threadIdx.x;
    const int m0 = blockIdx.x * 128, n0 = blockIdx.y * 64;
    const int wave = tid >> 6, lane = tid & 63;
    const int wm = (wave >> 1) << 6;      // 0 / 64
    const int wn = (wave & 1) << 5;       // 0 / 32
    const int l15 = lane & 15, quad = lane >> 4;

    const int ar = tid >> 1;              // 0..127
    const int ak = (tid & 1) << 4;        // 0 / 16 (fp16 units)
    const int wr = tid >> 2;              // 0..63
    const int wk = (tid & 3) << 3;        // 0,8,16,24

    f4v acc[4][2];
#pragma unroll
    for (int i = 0; i < 4; i++)
#pragma unroll
        for (int j = 0; j < 2; j++) acc[i][j] = (f4v){0.f, 0.f, 0.f, 0.f};

    const size_t abase = (size_t)(m0 + ar) * Kd + ak;
    const size_t wbase = (size_t)(n0 + wr) * Kd + wk;

    for (int k0 = 0; k0 < Kd; k0 += 32) {
        uint4 a0 = *(const uint4*)(Ahi + abase + k0);
        uint4 a1 = *(const uint4*)(Ahi + abase + k0 + 8);
        uint4 c0 = *(const uint4*)(Alo + abase + k0);
        uint4 c1 = *(const uint4*)(Alo + abase + k0 + 8);
        float4 w0 = *(const float4*)(W + wbase + k0);
        float4 w1 = *(const float4*)(W + wbase + k0 + 4);
        union { _Float16 h[8]; uint4 u; } wh, wl;
        float wf[8] = {w0.x, w0.y, w0.z, w0.w, w1.x, w1.y, w1.z, w1.w};
#pragma unroll
        for (int j = 0; j < 8; j++) {
            _Float16 h = (_Float16)wf[j];
            wh.h[j] = h;
            wl.h[j] = (_Float16)(wf[j] - (float)h);
        }
        __syncthreads();
        *(uint4*)(sAh + ar * LDA + ak)     = a0;
        *(uint4*)(sAh + ar * LDA + ak + 8) = a1;
        *(uint4*)(sAl + ar * LDA + ak)     = c0;
        *(uint4*)(sAl + ar * LDA + ak + 8) = c1;
        *(uint4*)(sWh + wr * LDA + wk) = wh.u;
        *(uint4*)(sWl + wr * LDA + wk) = wl.u;
        __syncthreads();

        h8v ah[4], alv[4], bh[2], bl[2];
#pragma unroll
        for (int i = 0; i < 4; i++) {
            ah[i]  = *(const h8v*)(sAh + (wm + (i << 4) + l15) * LDA + (quad << 3));
            alv[i] = *(const h8v*)(sAl + (wm + (i << 4) + l15) * LDA + (quad << 3));
        }
#pragma unroll
        for (int j = 0; j < 2; j++) {
            bh[j] = *(const h8v*)(sWh + (wn + (j << 4) + l15) * LDA + (quad << 3));
            bl[j] = *(const h8v*)(sWl + (wn + (j << 4) + l15) * LDA + (quad << 3));
        }
#pragma unroll
        for (int i = 0; i < 4; i++)
#pragma unroll
            for (int j = 0; j < 2; j++) {
                acc[i][j] = __builtin_amdgcn_mfma_f32_16x16x32_f16(ah[i],  bh[j], acc[i][j], 0, 0, 0);
                acc[i][j] = __builtin_amdgcn_mfma_f32_16x16x32_f16(ah[i],  bl[j], acc[i][j], 0, 0, 0);
                acc[i][j] = __builtin_amdgcn_mfma_f32_16x16x32_f16(alv[i], bh[j], acc[i][j], 0, 0, 0);
            }
    }
#pragma unroll
    for (int j = 0; j < 2; j++) {
        int col = n0 + wn + (j << 4) + l15;
        float bv = bias[col];
#pragma unroll
        for (int i = 0; i < 4; i++) {
            int row = m0 + wm + (i << 4) + (quad << 2);
#pragma unroll
            for (int r = 0; r < 4; r++)
                C[(size_t)(row + r) * N + col] = acc[i][j][r] + bv;
        }
    }
}

// ---------------------------------------------------------------------------
// 5) L2-normalize embed rows (in place) + f16 split + eqh = -0.5*||ehat||^2
__global__ __launch_bounds__(256) void k_l2norm(float* __restrict__ E,
                                                float* __restrict__ eqh,
                                                _Float16* __restrict__ Ehi,
                                                _Float16* __restrict__ Elo) {
    int tid = threadIdx.x;
    int row = blockIdx.x * 4 + (tid >> 6);
    int v = tid & 63;
    size_t off = ((size_t)row << 6) + v;
    float x = E[off];
    float ss = x * x;
#pragma unroll
    for (int o = 32; o; o >>= 1) ss += __shfl_xor(ss, o, 64);
    float inv = 1.f / (sqrtf(ss) + 1e-6f);
    float xn = x * inv;
    E[off] = xn;
    _Float16 hh = (_Float16)xn;
    Ehi[off] = hh;
    Elo[off] = (_Float16)(xn - (float)hh);
    if (v == 0) eqh[row] = -0.5f * (ss * inv * inv);
}

// ---------------------------------------------------------------------------
// 6a) split proj_w -> f16 hi/lo [v][d]. grid 48 x 256 (float4/thread)
__global__ __launch_bounds__(256) void k_wsplit(const float* __restrict__ pw,
                                                _Float16* __restrict__ pwhi,
                                                _Float16* __restrict__ pwlo) {
    int i = blockIdx.x * 256 + threadIdx.x;       // float4 index, 49152/4 total
    float4 w = ((const float4*)pw)[i];
    float wf[4] = {w.x, w.y, w.z, w.w};
    union { _Float16 h[4]; uint2 u; } uh, ul;
#pragma unroll
    for (int j = 0; j < 4; j++) {
        _Float16 h = (_Float16)wf[j];
        uh.h[j] = h;
        ul.h[j] = (_Float16)(wf[j] - (float)h);
    }
    *(uint2*)(pwhi + ((size_t)i << 2)) = uh.u;
    *(uint2*)(pwlo + ((size_t)i << 2)) = ul.u;
}

// ---------------------------------------------------------------------------
// 6b) projection GEMM, split-K: Hpart[ks][t][v] = sum_{d in chunk} h_in[b,d,t]*pw[v,d]
// A = h (m=t, transposed through LDS), B = pw-split (n=v, from global).
// grid (NT/128, 4), block 256 (4 waves, each 32t x 64v). 6 K-steps of 32.
__global__ __launch_bounds__(256) void k_proj_mfma(const float* __restrict__ h_in,
                                                   const _Float16* __restrict__ pwhi,
                                                   const _Float16* __restrict__ pwlo,
                                                   float* __restrict__ Hpart) {
    __shared__ float shA[128 * 33];
    const int tid = threadIdx.x;
    const int t0 = blockIdx.x * 128;
    const int ks = blockIdx.y;            // d-chunk [ks*192, ks*192+192)
    const int b = t0 >> 11;
    const int tloc0 = t0 & (TT_ - 1);
    const int wave = tid >> 6, lane = tid & 63;
    const int l15 = lane & 15, quad = lane >> 4;

    const int dl = tid >> 3;              // 0..31 (d within chunk step)
    const int tg = (tid & 7) << 4;        // 0,16,...,112 (t offset)

    f4v acc[2][4];
#pragma unroll
    for (int i = 0; i < 2; i++)
#pragma unroll
        for (int j = 0; j < 4; j++) acc[i][j] = (f4v){0.f, 0.f, 0.f, 0.f};

    for (int kk = 0; kk < 6; kk++) {
        int dd0 = ks * 192 + kk * 32;
        const float* src = h_in + ((size_t)(b * DD + dd0 + dl) << 11) + tloc0 + tg;
        float4 g0 = *(const float4*)(src);
        float4 g1 = *(const float4*)(src + 4);
        float4 g2 = *(const float4*)(src + 8);
        float4 g3 = *(const float4*)(src + 12);
        __syncthreads();
        float gv[16] = {g0.x, g0.y, g0.z, g0.w, g1.x, g1.y, g1.z, g1.w,
                        g2.x, g2.y, g2.z, g2.w, g3.x, g3.y, g3.z, g3.w};
#pragma unroll
        for (int i = 0; i < 16; i++) shA[(tg + i) * 33 + dl] = gv[i];
        __syncthreads();

        // A-frags (2 m-tiles per wave) from LDS, convert to hi/lo
        h8v ah[2], al[2];
#pragma unroll
        for (int mt = 0; mt < 2; mt++) {
            const float* ap = &shA[((wave << 5) + (mt << 4) + l15) * 33 + (quad << 3)];
            float4 a0 = *(const float4*)(ap);
            float4 a1 = *(const float4*)(ap + 4);
            float av[8] = {a0.x, a0.y, a0.z, a0.w, a1.x, a1.y, a1.z, a1.w};
#pragma unroll
            for (int j = 0; j < 8; j++) {
                _Float16 h = (_Float16)av[j];
                ah[mt][j] = h;
                al[mt][j] = (_Float16)(av[j] - (float)h);
            }
        }
        // B-frags (4 n-tiles) straight from global (L1/L2-resident)
#pragma unroll
        for (int nt = 0; nt < 4; nt++) {
            size_t wb = (size_t)((nt << 4) + l15) * DD + dd0 + (quad << 3);
            h8v bh = *(const h8v*)(pwhi + wb);
            h8v bl = *(const h8v*)(pwlo + wb);
#pragma unroll
            for (int mt = 0; mt < 2; mt++) {
                acc[mt][nt] = __builtin_amdgcn_mfma_f32_16x16x32_f16(ah[mt], bh, acc[mt][nt], 0, 0, 0);
                acc[mt][nt] = __builtin_amdgcn_mfma_f32_16x16x32_f16(ah[mt], bl, acc[mt][nt], 0, 0, 0);
                acc[mt][nt] = __builtin_amdgcn_mfma_f32_16x16x32_f16(al[mt], bh, acc[mt][nt], 0, 0, 0);
            }
        }
    }
    float* dst = Hpart + ((size_t)ks << 20);   // ks*16384*64
#pragma unroll
    for (int mt = 0; mt < 2; mt++) {
#pragma unroll
        for (int r = 0; r < 4; r++) {
            int t = t0 + (wave << 5) + (mt << 4) + (quad << 2) + r;
#pragma unroll
            for (int nt = 0; nt < 4; nt++)
                dst[((size_t)t << 6) + (nt << 4) + l15] = acc[mt][nt][r];
        }
    }
}

// ---------------------------------------------------------------------------
// 6c) sum 4 partials + bias, L2-normalize, f16 split. grid NT/64, block 256
__global__ __launch_bounds__(256) void k_hnorm(const float* __restrict__ Hpart,
                                               const float* __restrict__ pb,
                                               _Float16* __restrict__ Hhi,
                                               _Float16* __restrict__ Hlo) {
    __shared__ float ssp[4][64];
    int tid = threadIdx.x;
    int tt = tid & 63, vg = tid >> 6;
    int t = blockIdx.x * 64 + tt;
    size_t base = ((size_t)t << 6) + (vg << 4);
    float o[16];
#pragma unroll
    for (int u = 0; u < 4; u++) {
        float4 p0 = *(const float4*)(Hpart + (0u << 20) + base + (u << 2));
        float4 p1 = *(const float4*)(Hpart + (1u << 20) + base + (u << 2));
        float4 p2 = *(const float4*)(Hpart + (2u << 20) + base + (u << 2));
        float4 p3 = *(const float4*)(Hpart + (3u << 20) + base + (u << 2));
        o[u * 4 + 0] = p0.x + p1.x + p2.x + p3.x;
        o[u * 4 + 1] = p0.y + p1.y + p2.y + p3.y;
        o[u * 4 + 2] = p0.z + p1.z + p2.z + p3.z;
        o[u * 4 + 3] = p0.w + p1.w + p2.w + p3.w;
    }
    float sp = 0.f;
#pragma unroll
    for (int j = 0; j < 16; j++) {
        o[j] += pb[(vg << 4) + j];
        sp = fmaf(o[j], o[j], sp);
    }
    ssp[vg][tt] = sp;
    __syncthreads();
    float ss = ssp[0][tt] + ssp[1][tt] + ssp[2][tt] + ssp[3][tt];
    float inv = 1.f / (sqrtf(ss) + 1e-6f);
    union { _Float16 h[8]; uint4 u; } uh0, uh1, ul0, ul1;
#pragma unroll
    for (int j = 0; j < 16; j++) {
        float xn = o[j] * inv;
        _Float16 hh = (_Float16)xn;
        _Float16 ll = (_Float16)(xn - (float)hh);
        if (j < 8) { uh0.h[j] = hh; ul0.h[j] = ll; }
        else       { uh1.h[j - 8] = hh; ul1.h[j - 8] = ll; }
    }
    *(uint4*)(Hhi + base)     = uh0.u;
    *(uint4*)(Hhi + base + 8) = uh1.u;
    *(uint4*)(Hlo + base)     = ul0.u;
    *(uint4*)(Hlo + base + 8) = ul1.u;
}

// ---------------------------------------------------------------------------
// 7) MFMA argmax: s'(t,k) = hhat.ehat - 0.5*||ehat||^2, argmax over k.
// grid (NT/256, 4 k-splits), block 256.
__global__ __launch_bounds__(256) void k_argmax_mfma(const _Float16* __restrict__ Hhi,
                                                     const _Float16* __restrict__ Hlo,
                                                     const _Float16* __restrict__ Ehi,
                                                     const _Float16* __restrict__ Elo,
                                                     const float* __restrict__ eqh,
                                                     float* __restrict__ ps,
                                                     int* __restrict__ pi) {
    int tid = threadIdx.x;
    int wave = tid >> 6, lane = tid & 63;
    int l15 = lane & 15, quad = lane >> 4;
    int t0 = blockIdx.x * 256 + wave * 64;
    int kh = blockIdx.y;                  // 0..3, k-range [kh*1024, kh*1024+1024)

    h8v hh0[4], hh1[4], hl0[4], hl1[4];
#pragma unroll
    for (int s = 0; s < 4; s++) {
        size_t hb = (size_t)(t0 + (s << 4) + l15) * 64 + (quad << 3);
        hh0[s] = *(const h8v*)(Hhi + hb);
        hh1[s] = *(const h8v*)(Hhi + hb + 32);
        hl0[s] = *(const h8v*)(Hlo + hb);
        hl1[s] = *(const h8v*)(Hlo + hb + 32);
    }
    float best[4] = {-1e30f, -1e30f, -1e30f, -1e30f};
    int   idx[4]  = {0, 0, 0, 0};

    for (int it = 0; it < 64; it++) {
        int k0 = (kh << 10) + (it << 4);
        size_t eb = (size_t)(k0 + l15) * 64 + (quad << 3);
        h8v eh0 = *(const h8v*)(Ehi + eb);
        h8v eh1 = *(const h8v*)(Ehi + eb + 32);
        h8v el0 = *(const h8v*)(Elo + eb);
        h8v el1 = *(const h8v*)(Elo + eb + 32);
        float4 q4 = *(const float4*)(eqh + k0 + (quad << 2));
        f4v acc[4];
#pragma unroll
        for (int s = 0; s < 4; s++) acc[s] = (f4v){0.f, 0.f, 0.f, 0.f};
#pragma unroll
        for (int s = 0; s < 4; s++) acc[s] = __builtin_amdgcn_mfma_f32_16x16x32_f16(eh0, hh0[s], acc[s], 0, 0, 0);
#pragma unroll
        for (int s = 0; s < 4; s++) acc[s] = __builtin_amdgcn_mfma_f32_16x16x32_f16(eh1, hh1[s], acc[s], 0, 0, 0);
#pragma unroll
        for (int s = 0; s < 4; s++) acc[s] = __builtin_amdgcn_mfma_f32_16x16x32_f16(el0, hh0[s], acc[s], 0, 0, 0);
#pragma unroll
        for (int s = 0; s < 4; s++) acc[s] = __builtin_amdgcn_mfma_f32_16x16x32_f16(el1, hh1[s], acc[s], 0, 0, 0);
#pragma unroll
        for (int s = 0; s < 4; s++) acc[s] = __builtin_amdgcn_mfma_f32_16x16x32_f16(eh0, hl0[s], acc[s], 0, 0, 0);
#pragma unroll
        for (int s = 0; s < 4; s++) acc[s] = __builtin_amdgcn_mfma_f32_16x16x32_f16(eh1, hl1[s], acc[s], 0, 0, 0);
        float qv[4] = {q4.x, q4.y, q4.z, q4.w};
#pragma unroll
        for (int r = 0; r < 4; r++) {
            int k = k0 + (quad << 2) + r;
#pragma unroll
            for (int s = 0; s < 4; s++) {
                float sc = acc[s][r] + qv[r];
                if (sc > best[s]) { best[s] = sc; idx[s] = k; }
            }
        }
    }
#pragma unroll
    for (int m = 16; m <= 32; m <<= 1) {
#pragma unroll
        for (int s = 0; s < 4; s++) {
            float ob = __shfl_xor(best[s], m, 64);
            int   oi = __shfl_xor(idx[s], m, 64);
            if (ob > best[s] || (ob == best[s] && oi < idx[s])) { best[s] = ob; idx[s] = oi; }
        }
    }
    if (quad == 0) {
#pragma unroll
        for (int s = 0; s < 4; s++) {
            int t = t0 + (s << 4) + l15;
            ps[(size_t)t * 4 + kh] = best[s];
            pi[(size_t)t * 4 + kh] = idx[s];
        }
    }
}

// ---------------------------------------------------------------------------
// 8) merge 4 partials -> code; write vq_code (fp32, masked); gather G
__global__ __launch_bounds__(256) void k_merge(const float* __restrict__ ps,
                                               const int* __restrict__ pi,
                                               const int* __restrict__ mask,
                                               const float* __restrict__ E,
                                               float* __restrict__ G,
                                               float* __restrict__ outc) {
    __shared__ int codes[256];
    __shared__ int ms[256];
    int tid = threadIdx.x;
    int base = blockIdx.x << 8;
    int t = base + tid;
    float best = ps[(size_t)t * 4];
    int bi = pi[(size_t)t * 4];
#pragma unroll
    for (int s = 1; s < 4; s++) {
        float v = ps[(size_t)t * 4 + s];
        if (v > best) { best = v; bi = pi[(size_t)t * 4 + s]; }
    }
    int m = mask[t];
    codes[tid] = bi;
    ms[tid] = m;
    outc[t] = m ? (float)bi : 0.0f;
    __syncthreads();
    for (int i = tid; i < 256 * 16; i += 256) {
        int r = i >> 4, u = i & 15;
        float4 e = ms[r] ? ((const float4*)(E + ((size_t)codes[r] << 6)))[u]
                         : make_float4(0.f, 0.f, 0.f, 0.f);
        ((float4*)(G + ((size_t)(base + r) << 6)))[u] = e;
    }
}

// ---------------------------------------------------------------------------
// 9) fp32 VALU GEMM for the final quantized projection
__global__ __launch_bounds__(256) void k_gemm(const float* __restrict__ A,
                                              const float* __restrict__ W,
                                              const float* __restrict__ bias,
                                              float* __restrict__ C,
                                              int M, int N, int Kd) {
    __shared__ float As[16][68];
    __shared__ float Bs[16][68];
    int tid = threadIdx.x;
    int m0 = blockIdx.x * 64, n0 = blockIdx.y * 64;
    int lr = tid >> 2;
    int lk = (tid & 3) << 2;
    int tx = tid & 15, ty = tid >> 4;
    float acc[4][4] = {};
    for (int k0 = 0; k0 < Kd; k0 += 16) {
        float4 av = *(const float4*)(A + (size_t)(m0 + lr) * Kd + k0 + lk);
        float4 wv = *(const float4*)(W + (size_t)(n0 + lr) * Kd + k0 + lk);
        __syncthreads();
        As[lk + 0][lr] = av.x; As[lk + 1][lr] = av.y;
        As[lk + 2][lr] = av.z; As[lk + 3][lr] = av.w;
        Bs[lk + 0][lr] = wv.x; Bs[lk + 1][lr] = wv.y;
        Bs[lk + 2][lr] = wv.z; Bs[lk + 3][lr] = wv.w;
        __syncthreads();
#pragma unroll
        for (int k = 0; k < 16; k++) {
            const float4 a4 = *(const float4*)&As[k][ty << 2];
            const float4 b4 = *(const float4*)&Bs[k][tx << 2];
            float a[4] = {a4.x, a4.y, a4.z, a4.w};
            float b[4] = {b4.x, b4.y, b4.z, b4.w};
#pragma unroll
            for (int i = 0; i < 4; i++)
#pragma unroll
                for (int j = 0; j < 4; j++)
                    acc[i][j] = fmaf(a[i], b[j], acc[i][j]);
        }
    }
    float bv[4];
#pragma unroll
    for (int j = 0; j < 4; j++) bv[j] = bias[n0 + (tx << 2) + j];
#pragma unroll
    for (int i = 0; i < 4; i++) {
        size_t off = (size_t)(m0 + (ty << 2) + i) * N + n0 + (tx << 2);
        *(float4*)(C + off) =
            make_float4(acc[i][0] + bv[0], acc[i][1] + bv[1],
                        acc[i][2] + bv[2], acc[i][3] + bv[3]);
    }
}

// ---------------------------------------------------------------------------
extern "C" void kernel_launch(void* const* d_in, const int* in_sizes, int n_in,
                              void* d_out, int out_size, void* d_ws, size_t ws_size,
                              hipStream_t stream) {
    const float* h_in   = (const float*)d_in[0];
    const int*   amask  = (const int*)d_in[1];
    const float* proj_w = (const float*)d_in[2];
    const float* proj_b = (const float*)d_in[3];
    const float* inv_w  = (const float*)d_in[4];
    const float* inv_b  = (const float*)d_in[5];
    const float* w_in   = (const float*)d_in[6];
    const float* b_in   = (const float*)d_in[7];
    const float* w_mid  = (const float*)d_in[8];
    const float* b_mid  = (const float*)d_in[9];
    const float* w_out  = (const float*)d_in[10];
    const float* b_out  = (const float*)d_in[11];
    const float* gamma  = (const float*)d_in[12];
    const float* beta   = (const float*)d_in[13];

    float*     Y    = (float*)d_ws;                          // K*HID fp32
    _Float16*  Xhi  = (_Float16*)(Y + (size_t)KK * HID_);    // K*HID fp16
    _Float16*  Xlo  = Xhi + (size_t)KK * HID_;               // K*HID fp16
    float*     mv   = (float*)(Xlo + (size_t)KK * HID_);     // 2*HID
    float*     Emb  = mv + 2 * HID_;                         // K*VQ fp32
    float*     eqh  = Emb + (size_t)KK * VQ_;                // K
    float*     spart= eqh + KK;                              // 2*64*1024 stats partials
    _Float16*  pwhi = (_Float16*)(spart + 2 * 65536);        // VQ*DD f16
    _Float16*  pwlo = pwhi + (size_t)VQ_ * DD;               // VQ*DD f16
    // overlays:
    float*    Hpart = Y;                                     // 4*NT*64 fp32 == K*HID exactly
    _Float16* H16hi = Xhi;                                   // NT*64 f16
    _Float16* H16lo = H16hi + (size_t)NT * VQ_;              // NT*64 f16
    _Float16* E16hi = H16lo + (size_t)NT * VQ_;              // K*64 f16
    _Float16* E16lo = E16hi + (size_t)KK * VQ_;              // K*64 f16
    float*    ps    = (float*)(E16lo + (size_t)KK * VQ_);    // NT*4
    int*      pidx  = (int*)(ps + (size_t)NT * 4);           // NT*4
    float*    G     = (float*)(pidx + (size_t)NT * 4);       // NT*64 fp32

    float* out_q = (float*)d_out;                            // NT*DD fp32
    float* out_c = out_q + (size_t)NT * DD;                  // NT fp32

    // codebook MLP (fp16-split MFMA chain, fp32-equivalent precision)
    k_mlp_in<<<dim3(HID_ / 256, KK / 16), 256, 0, stream>>>(w_in, b_in, Y);
    k_bn_stats1<<<64, 256, 0, stream>>>(Y, spart);
    k_bn_stats2<<<4, 256, 0, stream>>>(spart, mv);
    k_bn_apply_split<<<KK * HID_ / 1024, 256, 0, stream>>>(Y, mv, gamma, beta, Xhi, Xlo);
    for (int i = 0; i < NMID; i++) {
        k_gemm_mfma<<<dim3(KK / 128, HID_ / 64), 256, 0, stream>>>(
            Xhi, Xlo, w_mid + (size_t)i * HID_ * HID_, b_mid + (size_t)i * HID_, Y,
            KK, HID_, HID_);
        k_bn_stats1<<<64, 256, 0, stream>>>(Y, spart);
        k_bn_stats2<<<4, 256, 0, stream>>>(spart, mv);
        k_bn_apply_split<<<KK * HID_ / 1024, 256, 0, stream>>>(Y, mv,
            gamma + (size_t)(i + 1) * HID_, beta + (size_t)(i + 1) * HID_, Xhi, Xlo);
    }
    k_gemm_mfma<<<dim3(KK / 128, VQ_ / 64), 256, 0, stream>>>(
        Xhi, Xlo, w_out, b_out, Emb, KK, VQ_, HID_);
    k_l2norm<<<KK / 4, 256, 0, stream>>>(Emb, eqh, E16hi, E16lo);

    // hidden-state path (split-K MFMA projection)
    k_wsplit<<<VQ_ * DD / 1024, 256, 0, stream>>>(proj_w, pwhi, pwlo);
    k_proj_mfma<<<dim3(NT / 128, 4), 256, 0, stream>>>(h_in, pwhi, pwlo, Hpart);
    k_hnorm<<<NT / 64, 256, 0, stream>>>(Hpart, proj_b, H16hi, H16lo);
    k_argmax_mfma<<<dim3(NT / 256, 4), 256, 0, stream>>>(
        H16hi, H16lo, E16hi, E16lo, eqh, ps, pidx);
    k_merge<<<NT / 256, 256, 0, stream>>>(ps, pidx, amask, Emb, G, out_c);
    k_gemm<<<dim3(NT / 64, DD / 64), 256, 0, stream>>>(
        G, inv_w, inv_b, out_q, NT, DD, VQ_);
}

// Round 8
// 539.816 us; speedup vs baseline: 1.9694x; 1.0275x over previous
//
#include <hip/hip_runtime.h>
#include <stddef.h>

// Problem constants
#define BB   8
#define TT_  2048
#define DD   768
#define VQ_  64
#define L2C  12
#define HID_ 1024
#define KK   4096
#define NMID 4
#define NT   (BB*TT_)         // 16384 positions

typedef _Float16 h8v __attribute__((ext_vector_type(8)));
typedef float    f4v __attribute__((ext_vector_type(4)));

#define LDA 40   // LDS row stride in fp16 units (32 + 8 pad -> 2-way bank alias = free)

// ---------------------------------------------------------------------------
// 1) bits @ mlp_w_in.T + b_in  ->  Y [K, HID]
__global__ __launch_bounds__(256) void k_mlp_in(const float* __restrict__ w_in,
                                                const float* __restrict__ b_in,
                                                float* __restrict__ X) {
    __shared__ float ws_[256 * 12];
    __shared__ float bs_[256];
    int tid = threadIdx.x;
    int h0  = blockIdx.x * 256;
    for (int i = tid; i < 256 * 12; i += 256) ws_[i] = w_in[h0 * 12 + i];
    bs_[tid] = b_in[h0 + tid];
    __syncthreads();
    float w[12];
#pragma unroll
    for (int l = 0; l < 12; l++) w[l] = ws_[tid * 12 + l];
    float bias = bs_[tid];
    int k0 = blockIdx.y * 16;
    for (int kk = 0; kk < 16; kk++) {
        int k = k0 + kk;
        float acc = bias;
#pragma unroll
        for (int l = 0; l < 12; l++)
            if ((k >> (11 - l)) & 1) acc += w[l];
        X[(size_t)k * HID_ + h0 + tid] = acc;
    }
}

// ---------------------------------------------------------------------------
// 2a) BN stats stage 1: 64 blocks, each reduces 64 rows x 1024 cols (coalesced)
__global__ __launch_bounds__(256) void k_bn_stats1(const float* __restrict__ Y,
                                                   float* __restrict__ part) {
    int b = blockIdx.x, t = threadIdx.x;
    const float* src = Y + ((size_t)b << 6) * HID_ + (t << 2);
    float sx = 0.f, sy = 0.f, sz = 0.f, sw = 0.f;
    float qx = 0.f, qy = 0.f, qz = 0.f, qw = 0.f;
    for (int r = 0; r < 64; r++) {
        float4 v = *(const float4*)(src + ((size_t)r << 10));
        sx += v.x; sy += v.y; sz += v.z; sw += v.w;
        qx += v.x * v.x; qy += v.y * v.y; qz += v.z * v.z; qw += v.w * v.w;
    }
    *(float4*)(part + ((size_t)b << 10) + (t << 2)) = make_float4(sx, sy, sz, sw);
    *(float4*)(part + 65536 + ((size_t)b << 10) + (t << 2)) = make_float4(qx, qy, qz, qw);
}

// 2b) BN stats stage 2: reduce 64 partials per column -> mean/var. grid 4 x 256
__global__ __launch_bounds__(256) void k_bn_stats2(const float* __restrict__ part,
                                                   float* __restrict__ mv) {
    int c = blockIdx.x * 256 + threadIdx.x;
    float s = 0.f, q = 0.f;
    for (int b = 0; b < 64; b++) {
        s += part[((size_t)b << 10) + c];
        q += part[65536 + ((size_t)b << 10) + c];
    }
    float m = s * (1.f / KK);
    float v = q * (1.f / KK) - m * m;
    mv[c] = m; mv[HID_ + c] = v;
}

// ---------------------------------------------------------------------------
// 3) BN apply + ReLU, emit fp16 hi/lo split pair. grid K*HID/1024, block 256
__global__ __launch_bounds__(256) void k_bn_apply_split(const float* __restrict__ Y,
                                                        const float* __restrict__ mv,
                                                        const float* __restrict__ gamma,
                                                        const float* __restrict__ beta,
                                                        _Float16* __restrict__ Xhi,
                                                        _Float16* __restrict__ Xlo) {
    int i = blockIdx.x * 256 + threadIdx.x;       // float4 index
    int c = (i << 2) & (HID_ - 1);
    float4 x = ((const float4*)Y)[i];
    float4 m = *(const float4*)(mv + c);
    float4 v = *(const float4*)(mv + HID_ + c);
    float4 g = *(const float4*)(gamma + c);
    float4 b = *(const float4*)(beta + c);
    float o[4];
    o[0] = fmaxf(0.f, (x.x - m.x) * (1.f / sqrtf(v.x + 1e-5f)) * g.x + b.x);
    o[1] = fmaxf(0.f, (x.y - m.y) * (1.f / sqrtf(v.y + 1e-5f)) * g.y + b.y);
    o[2] = fmaxf(0.f, (x.z - m.z) * (1.f / sqrtf(v.z + 1e-5f)) * g.z + b.z);
    o[3] = fmaxf(0.f, (x.w - m.w) * (1.f / sqrtf(v.w + 1e-5f)) * g.w + b.w);
    union { _Float16 h[4]; uint2 u; } uh, ul;
#pragma unroll
    for (int j = 0; j < 4; j++) {
        _Float16 h = (_Float16)o[j];
        uh.h[j] = h;
        ul.h[j] = (_Float16)(o[j] - (float)h);
    }
    *(uint2*)(Xhi + ((size_t)i << 2)) = uh.u;
    *(uint2*)(Xlo + ((size_t)i << 2)) = ul.u;
}

// ---------------------------------------------------------------------------
// 4) C[M,N] = (Ahi+Alo)[M,K] @ W[N,K]^T + bias[N], fp32-accurate via 3-term
//    fp16-split MFMA. Tile 128x64, BK=32, block 256 (4 waves, each 64x32).
__global__ __launch_bounds__(256) void k_gemm_mfma(const _Float16* __restrict__ Ahi,
                                                   const _Float16* __restrict__ Alo,
                                                   const float* __restrict__ W,
                                                   const float* __restrict__ bias,
                                                   float* __restrict__ C,
                                                   int M, int N, int Kd) {
    __shared__ _Float16 sAh[128 * LDA];
    __shared__ _Float16 sAl[128 * LDA];
    __shared__ _Float16 sWh[64 * LDA];
    __shared__ _Float16 sWl[64 * LDA];
    const int tid = threadIdx.x;
    const int m0 = blockIdx.x * 128, n0 = blockIdx.y * 64;
    const int wave = tid >> 6, lane = tid & 63;
    const int wm = (wave >> 1) << 6;      // 0 / 64
    const int wn = (wave & 1) << 5;       // 0 / 32
    const int l15 = lane & 15, quad = lane >> 4;

    const int ar = tid >> 1;              // 0..127
    const int ak = (tid & 1) << 4;        // 0 / 16 (fp16 units)
    const int wr = tid >> 2;              // 0..63
    const int wk = (tid & 3) << 3;        // 0,8,16,24

    f4v acc[4][2];
#pragma unroll
    for (int i = 0; i < 4; i++)
#pragma unroll
        for (int j = 0; j < 2; j++) acc[i][j] = (f4v){0.f, 0.f, 0.f, 0.f};

    const size_t abase = (size_t)(m0 + ar) * Kd + ak;
    const size_t wbase = (size_t)(n0 + wr) * Kd + wk;

    for (int k0 = 0; k0 < Kd; k0 += 32) {
        uint4 a0 = *(const uint4*)(Ahi + abase + k0);
        uint4 a1 = *(const uint4*)(Ahi + abase + k0 + 8);
        uint4 c0 = *(const uint4*)(Alo + abase + k0);
        uint4 c1 = *(const uint4*)(Alo + abase + k0 + 8);
        float4 w0 = *(const float4*)(W + wbase + k0);
        float4 w1 = *(const float4*)(W + wbase + k0 + 4);
        union { _Float16 h[8]; uint4 u; } wh, wl;
        float wf[8] = {w0.x, w0.y, w0.z, w0.w, w1.x, w1.y, w1.z, w1.w};
#pragma unroll
        for (int j = 0; j < 8; j++) {
            _Float16 h = (_Float16)wf[j];
            wh.h[j] = h;
            wl.h[j] = (_Float16)(wf[j] - (float)h);
        }
        __syncthreads();
        *(uint4*)(sAh + ar * LDA + ak)     = a0;
        *(uint4*)(sAh + ar * LDA + ak + 8) = a1;
        *(uint4*)(sAl + ar * LDA + ak)     = c0;
        *(uint4*)(sAl + ar * LDA + ak + 8) = c1;
        *(uint4*)(sWh + wr * LDA + wk) = wh.u;
        *(uint4*)(sWl + wr * LDA + wk) = wl.u;
        __syncthreads();

        h8v ah[4], alv[4], bh[2], bl[2];
#pragma unroll
        for (int i = 0; i < 4; i++) {
            ah[i]  = *(const h8v*)(sAh + (wm + (i << 4) + l15) * LDA + (quad << 3));
            alv[i] = *(const h8v*)(sAl + (wm + (i << 4) + l15) * LDA + (quad << 3));
        }
#pragma unroll
        for (int j = 0; j < 2; j++) {
            bh[j] = *(const h8v*)(sWh + (wn + (j << 4) + l15) * LDA + (quad << 3));
            bl[j] = *(const h8v*)(sWl + (wn + (j << 4) + l15) * LDA + (quad << 3));
        }
#pragma unroll
        for (int i = 0; i < 4; i++)
#pragma unroll
            for (int j = 0; j < 2; j++) {
                acc[i][j] = __builtin_amdgcn_mfma_f32_16x16x32_f16(ah[i],  bh[j], acc[i][j], 0, 0, 0);
                acc[i][j] = __builtin_amdgcn_mfma_f32_16x16x32_f16(ah[i],  bl[j], acc[i][j], 0, 0, 0);
                acc[i][j] = __builtin_amdgcn_mfma_f32_16x16x32_f16(alv[i], bh[j], acc[i][j], 0, 0, 0);
            }
    }
#pragma unroll
    for (int j = 0; j < 2; j++) {
        int col = n0 + wn + (j << 4) + l15;
        float bv = bias[col];
#pragma unroll
        for (int i = 0; i < 4; i++) {
            int row = m0 + wm + (i << 4) + (quad << 2);
#pragma unroll
            for (int r = 0; r < 4; r++)
                C[(size_t)(row + r) * N + col] = acc[i][j][r] + bv;
        }
    }
}

// ---------------------------------------------------------------------------
// 5) L2-normalize embed rows (in place) + f16 split + eqh = -0.5*||ehat||^2
__global__ __launch_bounds__(256) void k_l2norm(float* __restrict__ E,
                                                float* __restrict__ eqh,
                                                _Float16* __restrict__ Ehi,
                                                _Float16* __restrict__ Elo) {
    int tid = threadIdx.x;
    int row = blockIdx.x * 4 + (tid >> 6);
    int v = tid & 63;
    size_t off = ((size_t)row << 6) + v;
    float x = E[off];
    float ss = x * x;
#pragma unroll
    for (int o = 32; o; o >>= 1) ss += __shfl_xor(ss, o, 64);
    float inv = 1.f / (sqrtf(ss) + 1e-6f);
    float xn = x * inv;
    E[off] = xn;
    _Float16 hh = (_Float16)xn;
    Ehi[off] = hh;
    Elo[off] = (_Float16)(xn - (float)hh);
    if (v == 0) eqh[row] = -0.5f * (ss * inv * inv);
}

// ---------------------------------------------------------------------------
// 6a) split proj_w -> f16 hi/lo [v][d]. grid 48 x 256 (float4/thread)
__global__ __launch_bounds__(256) void k_wsplit(const float* __restrict__ pw,
                                                _Float16* __restrict__ pwhi,
                                                _Float16* __restrict__ pwlo) {
    int i = blockIdx.x * 256 + threadIdx.x;       // float4 index, 49152/4 total
    float4 w = ((const float4*)pw)[i];
    float wf[4] = {w.x, w.y, w.z, w.w};
    union { _Float16 h[4]; uint2 u; } uh, ul;
#pragma unroll
    for (int j = 0; j < 4; j++) {
        _Float16 h = (_Float16)wf[j];
        uh.h[j] = h;
        ul.h[j] = (_Float16)(wf[j] - (float)h);
    }
    *(uint2*)(pwhi + ((size_t)i << 2)) = uh.u;
    *(uint2*)(pwlo + ((size_t)i << 2)) = ul.u;
}

// ---------------------------------------------------------------------------
// 6b) projection GEMM, split-K: Hpart[ks][t][v] = sum_{d in chunk} h_in[b,d,t]*pw[v,d]
// grid (NT/128, 4), block 256 (4 waves, each 32t x 64v). 6 K-steps of 32.
__global__ __launch_bounds__(256) void k_proj_mfma(const float* __restrict__ h_in,
                                                   const _Float16* __restrict__ pwhi,
                                                   const _Float16* __restrict__ pwlo,
                                                   float* __restrict__ Hpart) {
    __shared__ float shA[128 * 33];
    const int tid = threadIdx.x;
    const int t0 = blockIdx.x * 128;
    const int ks = blockIdx.y;            // d-chunk [ks*192, ks*192+192)
    const int b = t0 >> 11;
    const int tloc0 = t0 & (TT_ - 1);
    const int wave = tid >> 6, lane = tid & 63;
    const int l15 = lane & 15, quad = lane >> 4;

    const int dl = tid >> 3;              // 0..31 (d within chunk step)
    const int tg = (tid & 7) << 4;        // 0,16,...,112 (t offset)

    f4v acc[2][4];
#pragma unroll
    for (int i = 0; i < 2; i++)
#pragma unroll
        for (int j = 0; j < 4; j++) acc[i][j] = (f4v){0.f, 0.f, 0.f, 0.f};

    for (int kk = 0; kk < 6; kk++) {
        int dd0 = ks * 192 + kk * 32;
        const float* src = h_in + ((size_t)(b * DD + dd0 + dl) << 11) + tloc0 + tg;
        float4 g0 = *(const float4*)(src);
        float4 g1 = *(const float4*)(src + 4);
        float4 g2 = *(const float4*)(src + 8);
        float4 g3 = *(const float4*)(src + 12);
        __syncthreads();
        float gv[16] = {g0.x, g0.y, g0.z, g0.w, g1.x, g1.y, g1.z, g1.w,
                        g2.x, g2.y, g2.z, g2.w, g3.x, g3.y, g3.z, g3.w};
#pragma unroll
        for (int i = 0; i < 16; i++) shA[(tg + i) * 33 + dl] = gv[i];
        __syncthreads();

        h8v ah[2], al[2];
#pragma unroll
        for (int mt = 0; mt < 2; mt++) {
            const float* ap = &shA[((wave << 5) + (mt << 4) + l15) * 33 + (quad << 3)];
            float4 a0 = *(const float4*)(ap);
            float4 a1 = *(const float4*)(ap + 4);
            float av[8] = {a0.x, a0.y, a0.z, a0.w, a1.x, a1.y, a1.z, a1.w};
#pragma unroll
            for (int j = 0; j < 8; j++) {
                _Float16 h = (_Float16)av[j];
                ah[mt][j] = h;
                al[mt][j] = (_Float16)(av[j] - (float)h);
            }
        }
#pragma unroll
        for (int nt = 0; nt < 4; nt++) {
            size_t wb = (size_t)((nt << 4) + l15) * DD + dd0 + (quad << 3);
            h8v bh = *(const h8v*)(pwhi + wb);
            h8v bl = *(const h8v*)(pwlo + wb);
#pragma unroll
            for (int mt = 0; mt < 2; mt++) {
                acc[mt][nt] = __builtin_amdgcn_mfma_f32_16x16x32_f16(ah[mt], bh, acc[mt][nt], 0, 0, 0);
                acc[mt][nt] = __builtin_amdgcn_mfma_f32_16x16x32_f16(ah[mt], bl, acc[mt][nt], 0, 0, 0);
                acc[mt][nt] = __builtin_amdgcn_mfma_f32_16x16x32_f16(al[mt], bh, acc[mt][nt], 0, 0, 0);
            }
        }
    }
    float* dst = Hpart + ((size_t)ks << 20);   // ks*16384*64
#pragma unroll
    for (int mt = 0; mt < 2; mt++) {
#pragma unroll
        for (int r = 0; r < 4; r++) {
            int t = t0 + (wave << 5) + (mt << 4) + (quad << 2) + r;
#pragma unroll
            for (int nt = 0; nt < 4; nt++)
                dst[((size_t)t << 6) + (nt << 4) + l15] = acc[mt][nt][r];
        }
    }
}

// ---------------------------------------------------------------------------
// 6c) sum 4 partials + bias, L2-normalize, f16 split. grid NT/64, block 256
__global__ __launch_bounds__(256) void k_hnorm(const float* __restrict__ Hpart,
                                               const float* __restrict__ pb,
                                               _Float16* __restrict__ Hhi,
                                               _Float16* __restrict__ Hlo) {
    __shared__ float ssp[4][64];
    int tid = threadIdx.x;
    int tt = tid & 63, vg = tid >> 6;
    int t = blockIdx.x * 64 + tt;
    size_t base = ((size_t)t << 6) + (vg << 4);
    float o[16];
#pragma unroll
    for (int u = 0; u < 4; u++) {
        float4 p0 = *(const float4*)(Hpart + (0u << 20) + base + (u << 2));
        float4 p1 = *(const float4*)(Hpart + (1u << 20) + base + (u << 2));
        float4 p2 = *(const float4*)(Hpart + (2u << 20) + base + (u << 2));
        float4 p3 = *(const float4*)(Hpart + (3u << 20) + base + (u << 2));
        o[u * 4 + 0] = p0.x + p1.x + p2.x + p3.x;
        o[u * 4 + 1] = p0.y + p1.y + p2.y + p3.y;
        o[u * 4 + 2] = p0.z + p1.z + p2.z + p3.z;
        o[u * 4 + 3] = p0.w + p1.w + p2.w + p3.w;
    }
    float sp = 0.f;
#pragma unroll
    for (int j = 0; j < 16; j++) {
        o[j] += pb[(vg << 4) + j];
        sp = fmaf(o[j], o[j], sp);
    }
    ssp[vg][tt] = sp;
    __syncthreads();
    float ss = ssp[0][tt] + ssp[1][tt] + ssp[2][tt] + ssp[3][tt];
    float inv = 1.f / (sqrtf(ss) + 1e-6f);
    union { _Float16 h[8]; uint4 u; } uh0, uh1, ul0, ul1;
#pragma unroll
    for (int j = 0; j < 16; j++) {
        float xn = o[j] * inv;
        _Float16 hh = (_Float16)xn;
        _Float16 ll = (_Float16)(xn - (float)hh);
        if (j < 8) { uh0.h[j] = hh; ul0.h[j] = ll; }
        else       { uh1.h[j - 8] = hh; ul1.h[j - 8] = ll; }
    }
    *(uint4*)(Hhi + base)     = uh0.u;
    *(uint4*)(Hhi + base + 8) = uh1.u;
    *(uint4*)(Hlo + base)     = ul0.u;
    *(uint4*)(Hlo + base + 8) = ul1.u;
}

// ---------------------------------------------------------------------------
// 7) MFMA argmax: s'(t,k) = hhat.ehat + (-0.5*||ehat||^2).
// NOTE: dot MUST be accumulated from zero-init C and q added AFTER — this
// rounding order is bit-matched to the validated r6 kernel. Folding q into
// the C init (r7) perturbed near-ties between near-duplicate codebook rows
// at distant indices and flipped vq_code. Do not reassociate.
// grid (NT/256, 8 k-splits), block 256; prefetched E-tiles, 32 iters of 16.
__global__ __launch_bounds__(256) void k_argmax_mfma(const _Float16* __restrict__ Hhi,
                                                     const _Float16* __restrict__ Hlo,
                                                     const _Float16* __restrict__ Ehi,
                                                     const _Float16* __restrict__ Elo,
                                                     const float* __restrict__ eqh,
                                                     float* __restrict__ ps,
                                                     int* __restrict__ pi) {
    int tid = threadIdx.x;
    int wave = tid >> 6, lane = tid & 63;
    int l15 = lane & 15, quad = lane >> 4;
    int t0 = blockIdx.x * 256 + wave * 64;
    int kh = blockIdx.y;                  // 0..7, k-range [kh*512, kh*512+512)
    const int kbase = kh << 9;

    h8v hh0[4], hh1[4], hl0[4], hl1[4];
#pragma unroll
    for (int s = 0; s < 4; s++) {
        size_t hb = (size_t)(t0 + (s << 4) + l15) * 64 + (quad << 3);
        hh0[s] = *(const h8v*)(Hhi + hb);
        hh1[s] = *(const h8v*)(Hhi + hb + 32);
        hl0[s] = *(const h8v*)(Hlo + hb);
        hl1[s] = *(const h8v*)(Hlo + hb + 32);
    }
    float best[4] = {-1e30f, -1e30f, -1e30f, -1e30f};
    int   idx[4]  = {0, 0, 0, 0};

    // prefetch iteration 0
    size_t eb = (size_t)(kbase + l15) * 64 + (quad << 3);
    h8v eh0 = *(const h8v*)(Ehi + eb);
    h8v eh1 = *(const h8v*)(Ehi + eb + 32);
    h8v el0 = *(const h8v*)(Elo + eb);
    h8v el1 = *(const h8v*)(Elo + eb + 32);
    float4 q4 = *(const float4*)(eqh + kbase + (quad << 2));

    for (int it = 0; it < 32; it++) {
        h8v ce0 = eh0, ce1 = eh1, cl0 = el0, cl1 = el1;
        float4 cq = q4;
        int k0 = kbase + (it << 4);
        int kn = k0 + 16;
        if (kn > KK - 16) kn = KK - 16;       // last iter: redundant-but-valid load
        size_t ebn = (size_t)(kn + l15) * 64 + (quad << 3);
        eh0 = *(const h8v*)(Ehi + ebn);
        eh1 = *(const h8v*)(Ehi + ebn + 32);
        el0 = *(const h8v*)(Elo + ebn);
        el1 = *(const h8v*)(Elo + ebn + 32);
        q4 = *(const float4*)(eqh + kn + (quad << 2));

        f4v acc[4];
#pragma unroll
        for (int s = 0; s < 4; s++) acc[s] = (f4v){0.f, 0.f, 0.f, 0.f};
#pragma unroll
        for (int s = 0; s < 4; s++) acc[s] = __builtin_amdgcn_mfma_f32_16x16x32_f16(ce0, hh0[s], acc[s], 0, 0, 0);
#pragma unroll
        for (int s = 0; s < 4; s++) acc[s] = __builtin_amdgcn_mfma_f32_16x16x32_f16(ce1, hh1[s], acc[s], 0, 0, 0);
#pragma unroll
        for (int s = 0; s < 4; s++) acc[s] = __builtin_amdgcn_mfma_f32_16x16x32_f16(cl0, hh0[s], acc[s], 0, 0, 0);
#pragma unroll
        for (int s = 0; s < 4; s++) acc[s] = __builtin_amdgcn_mfma_f32_16x16x32_f16(cl1, hh1[s], acc[s], 0, 0, 0);
#pragma unroll
        for (int s = 0; s < 4; s++) acc[s] = __builtin_amdgcn_mfma_f32_16x16x32_f16(ce0, hl0[s], acc[s], 0, 0, 0);
#pragma unroll
        for (int s = 0; s < 4; s++) acc[s] = __builtin_amdgcn_mfma_f32_16x16x32_f16(ce1, hl1[s], acc[s], 0, 0, 0);
        float qv[4] = {cq.x, cq.y, cq.z, cq.w};
#pragma unroll
        for (int r = 0; r < 4; r++) {
            int k = k0 + (quad << 2) + r;
#pragma unroll
            for (int s = 0; s < 4; s++) {
                float sc = acc[s][r] + qv[r];
                if (sc > best[s]) { best[s] = sc; idx[s] = k; }
            }
        }
    }
#pragma unroll
    for (int m = 16; m <= 32; m <<= 1) {
#pragma unroll
        for (int s = 0; s < 4; s++) {
            float ob = __shfl_xor(best[s], m, 64);
            int   oi = __shfl_xor(idx[s], m, 64);
            if (ob > best[s] || (ob == best[s] && oi < idx[s])) { best[s] = ob; idx[s] = oi; }
        }
    }
    if (quad == 0) {
#pragma unroll
        for (int s = 0; s < 4; s++) {
            int t = t0 + (s << 4) + l15;
            ps[(size_t)t * 8 + kh] = best[s];
            pi[(size_t)t * 8 + kh] = idx[s];
        }
    }
}

// ---------------------------------------------------------------------------
// 8) merge 8 partials -> code; write vq_code (fp32, masked); gather G
__global__ __launch_bounds__(256) void k_merge(const float* __restrict__ ps,
                                               const int* __restrict__ pi,
                                               const int* __restrict__ mask,
                                               const float* __restrict__ E,
                                               float* __restrict__ G,
                                               float* __restrict__ outc) {
    __shared__ int codes[256];
    __shared__ int ms[256];
    int tid = threadIdx.x;
    int base = blockIdx.x << 8;
    int t = base + tid;
    float best = ps[(size_t)t * 8];
    int bi = pi[(size_t)t * 8];
#pragma unroll
    for (int s = 1; s < 8; s++) {
        float v = ps[(size_t)t * 8 + s];
        if (v > best) { best = v; bi = pi[(size_t)t * 8 + s]; }
    }
    int m = mask[t];
    codes[tid] = bi;
    ms[tid] = m;
    outc[t] = m ? (float)bi : 0.0f;
    __syncthreads();
    for (int i = tid; i < 256 * 16; i += 256) {
        int r = i >> 4, u = i & 15;
        float4 e = ms[r] ? ((const float4*)(E + ((size_t)codes[r] << 6)))[u]
                         : make_float4(0.f, 0.f, 0.f, 0.f);
        ((float4*)(G + ((size_t)(base + r) << 6)))[u] = e;
    }
}

// ---------------------------------------------------------------------------
// 9) fp32 VALU GEMM for the final quantized projection
__global__ __launch_bounds__(256) void k_gemm(const float* __restrict__ A,
                                              const float* __restrict__ W,
                                              const float* __restrict__ bias,
                                              float* __restrict__ C,
                                              int M, int N, int Kd) {
    __shared__ float As[16][68];
    __shared__ float Bs[16][68];
    int tid = threadIdx.x;
    int m0 = blockIdx.x * 64, n0 = blockIdx.y * 64;
    int lr = tid >> 2;
    int lk = (tid & 3) << 2;
    int tx = tid & 15, ty = tid >> 4;
    float acc[4][4] = {};
    for (int k0 = 0; k0 < Kd; k0 += 16) {
        float4 av = *(const float4*)(A + (size_t)(m0 + lr) * Kd + k0 + lk);
        float4 wv = *(const float4*)(W + (size_t)(n0 + lr) * Kd + k0 + lk);
        __syncthreads();
        As[lk + 0][lr] = av.x; As[lk + 1][lr] = av.y;
        As[lk + 2][lr] = av.z; As[lk + 3][lr] = av.w;
        Bs[lk + 0][lr] = wv.x; Bs[lk + 1][lr] = wv.y;
        Bs[lk + 2][lr] = wv.z; Bs[lk + 3][lr] = wv.w;
        __syncthreads();
#pragma unroll
        for (int k = 0; k < 16; k++) {
            const float4 a4 = *(const float4*)&As[k][ty << 2];
            const float4 b4 = *(const float4*)&Bs[k][tx << 2];
            float a[4] = {a4.x, a4.y, a4.z, a4.w};
            float b[4] = {b4.x, b4.y, b4.z, b4.w};
#pragma unroll
            for (int i = 0; i < 4; i++)
#pragma unroll
                for (int j = 0; j < 4; j++)
                    acc[i][j] = fmaf(a[i], b[j], acc[i][j]);
        }
    }
    float bv[4];
#pragma unroll
    for (int j = 0; j < 4; j++) bv[j] = bias[n0 + (tx << 2) + j];
#pragma unroll
    for (int i = 0; i < 4; i++) {
        size_t off = (size_t)(m0 + (ty << 2) + i) * N + n0 + (tx << 2);
        *(float4*)(C + off) =
            make_float4(acc[i][0] + bv[0], acc[i][1] + bv[1],
                        acc[i][2] + bv[2], acc[i][3] + bv[3]);
    }
}

// ---------------------------------------------------------------------------
extern "C" void kernel_launch(void* const* d_in, const int* in_sizes, int n_in,
                              void* d_out, int out_size, void* d_ws, size_t ws_size,
                              hipStream_t stream) {
    const float* h_in   = (const float*)d_in[0];
    const int*   amask  = (const int*)d_in[1];
    const float* proj_w = (const float*)d_in[2];
    const float* proj_b = (const float*)d_in[3];
    const float* inv_w  = (const float*)d_in[4];
    const float* inv_b  = (const float*)d_in[5];
    const float* w_in   = (const float*)d_in[6];
    const float* b_in   = (const float*)d_in[7];
    const float* w_mid  = (const float*)d_in[8];
    const float* b_mid  = (const float*)d_in[9];
    const float* w_out  = (const float*)d_in[10];
    const float* b_out  = (const float*)d_in[11];
    const float* gamma  = (const float*)d_in[12];
    const float* beta   = (const float*)d_in[13];

    float*     Y    = (float*)d_ws;                          // K*HID fp32
    _Float16*  Xhi  = (_Float16*)(Y + (size_t)KK * HID_);    // K*HID fp16
    _Float16*  Xlo  = Xhi + (size_t)KK * HID_;               // K*HID fp16
    float*     mv   = (float*)(Xlo + (size_t)KK * HID_);     // 2*HID
    float*     Emb  = mv + 2 * HID_;                         // K*VQ fp32
    float*     eqh  = Emb + (size_t)KK * VQ_;                // K
    float*     spart= eqh + KK;                              // 2*64*1024 stats partials
    _Float16*  pwhi = (_Float16*)(spart + 2 * 65536);        // VQ*DD f16
    _Float16*  pwlo = pwhi + (size_t)VQ_ * DD;               // VQ*DD f16
    // overlays:
    float*    Hpart = Y;                                     // 4*NT*64 fp32 == K*HID exactly
    _Float16* H16hi = Xhi;                                   // NT*64 f16
    _Float16* H16lo = H16hi + (size_t)NT * VQ_;              // NT*64 f16
    _Float16* E16hi = H16lo + (size_t)NT * VQ_;              // K*64 f16
    _Float16* E16lo = E16hi + (size_t)KK * VQ_;              // K*64 f16
    float*    ps    = (float*)(E16lo + (size_t)KK * VQ_);    // NT*8
    int*      pidx  = (int*)(ps + (size_t)NT * 8);           // NT*8
    float*    G     = (float*)(pidx + (size_t)NT * 8);       // NT*64 fp32

    float* out_q = (float*)d_out;                            // NT*DD fp32
    float* out_c = out_q + (size_t)NT * DD;                  // NT fp32

    // codebook MLP (fp16-split MFMA chain, fp32-equivalent precision)
    k_mlp_in<<<dim3(HID_ / 256, KK / 16), 256, 0, stream>>>(w_in, b_in, Y);
    k_bn_stats1<<<64, 256, 0, stream>>>(Y, spart);
    k_bn_stats2<<<4, 256, 0, stream>>>(spart, mv);
    k_bn_apply_split<<<KK * HID_ / 1024, 256, 0, stream>>>(Y, mv, gamma, beta, Xhi, Xlo);
    for (int i = 0; i < NMID; i++) {
        k_gemm_mfma<<<dim3(KK / 128, HID_ / 64), 256, 0, stream>>>(
            Xhi, Xlo, w_mid + (size_t)i * HID_ * HID_, b_mid + (size_t)i * HID_, Y,
            KK, HID_, HID_);
        k_bn_stats1<<<64, 256, 0, stream>>>(Y, spart);
        k_bn_stats2<<<4, 256, 0, stream>>>(spart, mv);
        k_bn_apply_split<<<KK * HID_ / 1024, 256, 0, stream>>>(Y, mv,
            gamma + (size_t)(i + 1) * HID_, beta + (size_t)(i + 1) * HID_, Xhi, Xlo);
    }
    k_gemm_mfma<<<dim3(KK / 128, VQ_ / 64), 256, 0, stream>>>(
        Xhi, Xlo, w_out, b_out, Emb, KK, VQ_, HID_);
    k_l2norm<<<KK / 4, 256, 0, stream>>>(Emb, eqh, E16hi, E16lo);

    // hidden-state path (split-K MFMA projection)
    k_wsplit<<<VQ_ * DD / 1024, 256, 0, stream>>>(proj_w, pwhi, pwlo);
    k_proj_mfma<<<dim3(NT / 128, 4), 256, 0, stream>>>(h_in, pwhi, pwlo, Hpart);
    k_hnorm<<<NT / 64, 256, 0, stream>>>(Hpart, proj_b, H16hi, H16lo);
    k_argmax_mfma<<<dim3(NT / 256, 8), 256, 0, stream>>>(
        H16hi, H16lo, E16hi, E16lo, eqh, ps, pidx);
    k_merge<<<NT / 256, 256, 0, stream>>>(ps, pidx, amask, Emb, G, out_c);
    k_gemm<<<dim3(NT / 64, DD / 64), 256, 0, stream>>>(
        G, inv_w, inv_b, out_q, NT, DD, VQ_);
}

// Round 10
// 515.094 us; speedup vs baseline: 2.0640x; 1.0480x over previous
//
#include <hip/hip_runtime.h>
#include <stddef.h>

// Problem constants
#define BB   8
#define TT_  2048
#define DD   768
#define VQ_  64
#define L2C  12
#define HID_ 1024
#define KK   4096
#define NMID 4
#define NT   (BB*TT_)         // 16384 positions

typedef _Float16 h8v __attribute__((ext_vector_type(8)));
typedef float    f4v __attribute__((ext_vector_type(4)));

#define LDA 40   // LDS row stride in fp16 units (32 + 8 pad -> 2-way bank alias = free)

// ---------------------------------------------------------------------------
// 1) bits @ mlp_w_in.T + b_in  ->  Y [K, HID]
__global__ __launch_bounds__(256) void k_mlp_in(const float* __restrict__ w_in,
                                                const float* __restrict__ b_in,
                                                float* __restrict__ X) {
    __shared__ float ws_[256 * 12];
    __shared__ float bs_[256];
    int tid = threadIdx.x;
    int h0  = blockIdx.x * 256;
    for (int i = tid; i < 256 * 12; i += 256) ws_[i] = w_in[h0 * 12 + i];
    bs_[tid] = b_in[h0 + tid];
    __syncthreads();
    float w[12];
#pragma unroll
    for (int l = 0; l < 12; l++) w[l] = ws_[tid * 12 + l];
    float bias = bs_[tid];
    int k0 = blockIdx.y * 16;
    for (int kk = 0; kk < 16; kk++) {
        int k = k0 + kk;
        float acc = bias;
#pragma unroll
        for (int l = 0; l < 12; l++)
            if ((k >> (11 - l)) & 1) acc += w[l];
        X[(size_t)k * HID_ + h0 + tid] = acc;
    }
}

// ---------------------------------------------------------------------------
// 2a) BN stats stage 1. grid (64 row-chunks, 4 col-groups), block 256.
// One column per thread, 64 rows ascending — BIT-IDENTICAL per-column chain
// to the validated r8 version. BN stats feed embed feed argmax (knife-edge
// ties, see r7 note at k_argmax_mfma) — do not reorder.
__global__ __launch_bounds__(256) void k_bn_stats1(const float* __restrict__ Y,
                                                   float* __restrict__ part) {
    int b = blockIdx.x;
    int c = blockIdx.y * 256 + threadIdx.x;
    const float* src = Y + ((size_t)b << 6) * HID_ + c;
    float s = 0.f, q = 0.f;
    for (int r = 0; r < 64; r++) {
        float v = src[(size_t)r << 10];
        s += v; q += v * v;
    }
    part[((size_t)b << 10) + c] = s;
    part[65536 + ((size_t)b << 10) + c] = q;
}

// 2b) BN stats stage 2: reduce 64 partials per column -> mean/var. grid 4 x 256
__global__ __launch_bounds__(256) void k_bn_stats2(const float* __restrict__ part,
                                                   float* __restrict__ mv) {
    int c = blockIdx.x * 256 + threadIdx.x;
    float s = 0.f, q = 0.f;
    for (int b = 0; b < 64; b++) {
        s += part[((size_t)b << 10) + c];
        q += part[65536 + ((size_t)b << 10) + c];
    }
    float m = s * (1.f / KK);
    float v = q * (1.f / KK) - m * m;
    mv[c] = m; mv[HID_ + c] = v;
}

// ---------------------------------------------------------------------------
// 3) BN apply + ReLU, emit fp16 hi/lo split pair. grid K*HID/1024, block 256
__global__ __launch_bounds__(256) void k_bn_apply_split(const float* __restrict__ Y,
                                                        const float* __restrict__ mv,
                                                        const float* __restrict__ gamma,
                                                        const float* __restrict__ beta,
                                                        _Float16* __restrict__ Xhi,
                                                        _Float16* __restrict__ Xlo) {
    int i = blockIdx.x * 256 + threadIdx.x;       // float4 index
    int c = (i << 2) & (HID_ - 1);
    float4 x = ((const float4*)Y)[i];
    float4 m = *(const float4*)(mv + c);
    float4 v = *(const float4*)(mv + HID_ + c);
    float4 g = *(const float4*)(gamma + c);
    float4 b = *(const float4*)(beta + c);
    float o[4];
    o[0] = fmaxf(0.f, (x.x - m.x) * (1.f / sqrtf(v.x + 1e-5f)) * g.x + b.x);
    o[1] = fmaxf(0.f, (x.y - m.y) * (1.f / sqrtf(v.y + 1e-5f)) * g.y + b.y);
    o[2] = fmaxf(0.f, (x.z - m.z) * (1.f / sqrtf(v.z + 1e-5f)) * g.z + b.z);
    o[3] = fmaxf(0.f, (x.w - m.w) * (1.f / sqrtf(v.w + 1e-5f)) * g.w + b.w);
    union { _Float16 h[4]; uint2 u; } uh, ul;
#pragma unroll
    for (int j = 0; j < 4; j++) {
        _Float16 h = (_Float16)o[j];
        uh.h[j] = h;
        ul.h[j] = (_Float16)(o[j] - (float)h);
    }
    *(uint2*)(Xhi + ((size_t)i << 2)) = uh.u;
    *(uint2*)(Xlo + ((size_t)i << 2)) = ul.u;
}

// ---------------------------------------------------------------------------
// 4) C[M,N] = (Ahi+Alo)[M,K] @ W[N,K]^T + bias[N], fp32-accurate via 3-term
//    fp16-split MFMA. Tile 128x64, BK=32, block 256 (4 waves, each 64x32).
__global__ __launch_bounds__(256) void k_gemm_mfma(const _Float16* __restrict__ Ahi,
                                                   const _Float16* __restrict__ Alo,
                                                   const float* __restrict__ W,
                                                   const float* __restrict__ bias,
                                                   float* __restrict__ C,
                                                   int M, int N, int Kd) {
    __shared__ _Float16 sAh[128 * LDA];
    __shared__ _Float16 sAl[128 * LDA];
    __shared__ _Float16 sWh[64 * LDA];
    __shared__ _Float16 sWl[64 * LDA];
    const int tid = threadIdx.x;
    const int m0 = blockIdx.x * 128, n0 = blockIdx.y * 64;
    const int wave = tid >> 6, lane = tid & 63;
    const int wm = (wave >> 1) << 6;      // 0 / 64
    const int wn = (wave & 1) << 5;       // 0 / 32
    const int l15 = lane & 15, quad = lane >> 4;

    const int ar = tid >> 1;              // 0..127
    const int ak = (tid & 1) << 4;        // 0 / 16 (fp16 units)
    const int wr = tid >> 2;              // 0..63
    const int wk = (tid & 3) << 3;        // 0,8,16,24

    f4v acc[4][2];
#pragma unroll
    for (int i = 0; i < 4; i++)
#pragma unroll
        for (int j = 0; j < 2; j++) acc[i][j] = (f4v){0.f, 0.f, 0.f, 0.f};

    const size_t abase = (size_t)(m0 + ar) * Kd + ak;
    const size_t wbase = (size_t)(n0 + wr) * Kd + wk;

    for (int k0 = 0; k0 < Kd; k0 += 32) {
        uint4 a0 = *(const uint4*)(Ahi + abase + k0);
        uint4 a1 = *(const uint4*)(Ahi + abase + k0 + 8);
        uint4 c0 = *(const uint4*)(Alo + abase + k0);
        uint4 c1 = *(const uint4*)(Alo + abase + k0 + 8);
        float4 w0 = *(const float4*)(W + wbase + k0);
        float4 w1 = *(const float4*)(W + wbase + k0 + 4);
        union { _Float16 h[8]; uint4 u; } wh, wl;
        float wf[8] = {w0.x, w0.y, w0.z, w0.w, w1.x, w1.y, w1.z, w1.w};
#pragma unroll
        for (int j = 0; j < 8; j++) {
            _Float16 h = (_Float16)wf[j];
            wh.h[j] = h;
            wl.h[j] = (_Float16)(wf[j] - (float)h);
        }
        __syncthreads();
        *(uint4*)(sAh + ar * LDA + ak)     = a0;
        *(uint4*)(sAh + ar * LDA + ak + 8) = a1;
        *(uint4*)(sAl + ar * LDA + ak)     = c0;
        *(uint4*)(sAl + ar * LDA + ak + 8) = c1;
        *(uint4*)(sWh + wr * LDA + wk) = wh.u;
        *(uint4*)(sWl + wr * LDA + wk) = wl.u;
        __syncthreads();

        h8v ah[4], alv[4], bh[2], bl[2];
#pragma unroll
        for (int i = 0; i < 4; i++) {
            ah[i]  = *(const h8v*)(sAh + (wm + (i << 4) + l15) * LDA + (quad << 3));
            alv[i] = *(const h8v*)(sAl + (wm + (i << 4) + l15) * LDA + (quad << 3));
        }
#pragma unroll
        for (int j = 0; j < 2; j++) {
            bh[j] = *(const h8v*)(sWh + (wn + (j << 4) + l15) * LDA + (quad << 3));
            bl[j] = *(const h8v*)(sWl + (wn + (j << 4) + l15) * LDA + (quad << 3));
        }
#pragma unroll
        for (int i = 0; i < 4; i++)
#pragma unroll
            for (int j = 0; j < 2; j++) {
                acc[i][j] = __builtin_amdgcn_mfma_f32_16x16x32_f16(ah[i],  bh[j], acc[i][j], 0, 0, 0);
                acc[i][j] = __builtin_amdgcn_mfma_f32_16x16x32_f16(ah[i],  bl[j], acc[i][j], 0, 0, 0);
                acc[i][j] = __builtin_amdgcn_mfma_f32_16x16x32_f16(alv[i], bh[j], acc[i][j], 0, 0, 0);
            }
    }
#pragma unroll
    for (int j = 0; j < 2; j++) {
        int col = n0 + wn + (j << 4) + l15;
        float bv = bias[col];
#pragma unroll
        for (int i = 0; i < 4; i++) {
            int row = m0 + wm + (i << 4) + (quad << 2);
#pragma unroll
            for (int r = 0; r < 4; r++)
                C[(size_t)(row + r) * N + col] = acc[i][j][r] + bv;
        }
    }
}

// ---------------------------------------------------------------------------
// 5) L2-normalize embed rows (in place) + f16 split + eqh = -0.5*||ehat||^2
__global__ __launch_bounds__(256) void k_l2norm(float* __restrict__ E,
                                                float* __restrict__ eqh,
                                                _Float16* __restrict__ Ehi,
                                                _Float16* __restrict__ Elo) {
    int tid = threadIdx.x;
    int row = blockIdx.x * 4 + (tid >> 6);
    int v = tid & 63;
    size_t off = ((size_t)row << 6) + v;
    float x = E[off];
    float ss = x * x;
#pragma unroll
    for (int o = 32; o; o >>= 1) ss += __shfl_xor(ss, o, 64);
    float inv = 1.f / (sqrtf(ss) + 1e-6f);
    float xn = x * inv;
    E[off] = xn;
    _Float16 hh = (_Float16)xn;
    Ehi[off] = hh;
    Elo[off] = (_Float16)(xn - (float)hh);
    if (v == 0) eqh[row] = -0.5f * (ss * inv * inv);
}

// ---------------------------------------------------------------------------
// 6a) split proj_w -> f16 hi/lo [v][d]. grid 48 x 256 (float4/thread)
__global__ __launch_bounds__(256) void k_wsplit(const float* __restrict__ pw,
                                                _Float16* __restrict__ pwhi,
                                                _Float16* __restrict__ pwlo) {
    int i = blockIdx.x * 256 + threadIdx.x;       // float4 index, 49152/4 total
    float4 w = ((const float4*)pw)[i];
    float wf[4] = {w.x, w.y, w.z, w.w};
    union { _Float16 h[4]; uint2 u; } uh, ul;
#pragma unroll
    for (int j = 0; j < 4; j++) {
        _Float16 h = (_Float16)wf[j];
        uh.h[j] = h;
        ul.h[j] = (_Float16)(wf[j] - (float)h);
    }
    *(uint2*)(pwhi + ((size_t)i << 2)) = uh.u;
    *(uint2*)(pwlo + ((size_t)i << 2)) = ul.u;
}

// 6a') convert inv_w -> f16 hi only [d][v] (final projection is not
// argmax-feeding; threshold 81.92 >> f16 error). grid 48 x 256.
// iwh lives in the OVERLAY region (dead Xhi/Xlo) — ws high-water must stay
// at the r8-proven footprint (r9 extended the static region by 96 KB and
// the process died with a GPU memory fault; suspected ws_size overrun).
__global__ __launch_bounds__(256) void k_cvt_inv(const float* __restrict__ iw,
                                                 _Float16* __restrict__ iwh) {
    int i = blockIdx.x * 256 + threadIdx.x;       // float4 index, 49152/4 total
    float4 w = ((const float4*)iw)[i];
    union { _Float16 h[4]; uint2 u; } uh;
    uh.h[0] = (_Float16)w.x; uh.h[1] = (_Float16)w.y;
    uh.h[2] = (_Float16)w.z; uh.h[3] = (_Float16)w.w;
    *(uint2*)(iwh + ((size_t)i << 2)) = uh.u;
}

// ---------------------------------------------------------------------------
// 6b) projection GEMM, split-K: Hpart[ks][t][v] = sum_{d in chunk} h_in[b,d,t]*pw[v,d]
// grid (NT/128, 4), block 256 (4 waves, each 32t x 64v). 6 K-steps of 32.
__global__ __launch_bounds__(256) void k_proj_mfma(const float* __restrict__ h_in,
                                                   const _Float16* __restrict__ pwhi,
                                                   const _Float16* __restrict__ pwlo,
                                                   float* __restrict__ Hpart) {
    __shared__ float shA[128 * 33];
    const int tid = threadIdx.x;
    const int t0 = blockIdx.x * 128;
    const int ks = blockIdx.y;            // d-chunk [ks*192, ks*192+192)
    const int b = t0 >> 11;
    const int tloc0 = t0 & (TT_ - 1);
    const int wave = tid >> 6, lane = tid & 63;
    const int l15 = lane & 15, quad = lane >> 4;

    const int dl = tid >> 3;              // 0..31 (d within chunk step)
    const int tg = (tid & 7) << 4;        // 0,16,...,112 (t offset)

    f4v acc[2][4];
#pragma unroll
    for (int i = 0; i < 2; i++)
#pragma unroll
        for (int j = 0; j < 4; j++) acc[i][j] = (f4v){0.f, 0.f, 0.f, 0.f};

    for (int kk = 0; kk < 6; kk++) {
        int dd0 = ks * 192 + kk * 32;
        const float* src = h_in + ((size_t)(b * DD + dd0 + dl) << 11) + tloc0 + tg;
        float4 g0 = *(const float4*)(src);
        float4 g1 = *(const float4*)(src + 4);
        float4 g2 = *(const float4*)(src + 8);
        float4 g3 = *(const float4*)(src + 12);
        __syncthreads();
        float gv[16] = {g0.x, g0.y, g0.z, g0.w, g1.x, g1.y, g1.z, g1.w,
                        g2.x, g2.y, g2.z, g2.w, g3.x, g3.y, g3.z, g3.w};
#pragma unroll
        for (int i = 0; i < 16; i++) shA[(tg + i) * 33 + dl] = gv[i];
        __syncthreads();

        h8v ah[2], al[2];
#pragma unroll
        for (int mt = 0; mt < 2; mt++) {
            const float* ap = &shA[((wave << 5) + (mt << 4) + l15) * 33 + (quad << 3)];
            float4 a0 = *(const float4*)(ap);
            float4 a1 = *(const float4*)(ap + 4);
            float av[8] = {a0.x, a0.y, a0.z, a0.w, a1.x, a1.y, a1.z, a1.w};
#pragma unroll
            for (int j = 0; j < 8; j++) {
                _Float16 h = (_Float16)av[j];
                ah[mt][j] = h;
                al[mt][j] = (_Float16)(av[j] - (float)h);
            }
        }
#pragma unroll
        for (int nt = 0; nt < 4; nt++) {
            size_t wb = (size_t)((nt << 4) + l15) * DD + dd0 + (quad << 3);
            h8v bh = *(const h8v*)(pwhi + wb);
            h8v bl = *(const h8v*)(pwlo + wb);
#pragma unroll
            for (int mt = 0; mt < 2; mt++) {
                acc[mt][nt] = __builtin_amdgcn_mfma_f32_16x16x32_f16(ah[mt], bh, acc[mt][nt], 0, 0, 0);
                acc[mt][nt] = __builtin_amdgcn_mfma_f32_16x16x32_f16(ah[mt], bl, acc[mt][nt], 0, 0, 0);
                acc[mt][nt] = __builtin_amdgcn_mfma_f32_16x16x32_f16(al[mt], bh, acc[mt][nt], 0, 0, 0);
            }
        }
    }
    float* dst = Hpart + ((size_t)ks << 20);   // ks*16384*64
#pragma unroll
    for (int mt = 0; mt < 2; mt++) {
#pragma unroll
        for (int r = 0; r < 4; r++) {
            int t = t0 + (wave << 5) + (mt << 4) + (quad << 2) + r;
#pragma unroll
            for (int nt = 0; nt < 4; nt++)
                dst[((size_t)t << 6) + (nt << 4) + l15] = acc[mt][nt][r];
        }
    }
}

// ---------------------------------------------------------------------------
// 6c) sum 4 partials + bias, L2-normalize, f16 split. grid NT/64, block 256
__global__ __launch_bounds__(256) void k_hnorm(const float* __restrict__ Hpart,
                                               const float* __restrict__ pb,
                                               _Float16* __restrict__ Hhi,
                                               _Float16* __restrict__ Hlo) {
    __shared__ float ssp[4][64];
    int tid = threadIdx.x;
    int tt = tid & 63, vg = tid >> 6;
    int t = blockIdx.x * 64 + tt;
    size_t base = ((size_t)t << 6) + (vg << 4);
    float o[16];
#pragma unroll
    for (int u = 0; u < 4; u++) {
        float4 p0 = *(const float4*)(Hpart + (0u << 20) + base + (u << 2));
        float4 p1 = *(const float4*)(Hpart + (1u << 20) + base + (u << 2));
        float4 p2 = *(const float4*)(Hpart + (2u << 20) + base + (u << 2));
        float4 p3 = *(const float4*)(Hpart + (3u << 20) + base + (u << 2));
        o[u * 4 + 0] = p0.x + p1.x + p2.x + p3.x;
        o[u * 4 + 1] = p0.y + p1.y + p2.y + p3.y;
        o[u * 4 + 2] = p0.z + p1.z + p2.z + p3.z;
        o[u * 4 + 3] = p0.w + p1.w + p2.w + p3.w;
    }
    float sp = 0.f;
#pragma unroll
    for (int j = 0; j < 16; j++) {
        o[j] += pb[(vg << 4) + j];
        sp = fmaf(o[j], o[j], sp);
    }
    ssp[vg][tt] = sp;
    __syncthreads();
    float ss = ssp[0][tt] + ssp[1][tt] + ssp[2][tt] + ssp[3][tt];
    float inv = 1.f / (sqrtf(ss) + 1e-6f);
    union { _Float16 h[8]; uint4 u; } uh0, uh1, ul0, ul1;
#pragma unroll
    for (int j = 0; j < 16; j++) {
        float xn = o[j] * inv;
        _Float16 hh = (_Float16)xn;
        _Float16 ll = (_Float16)(xn - (float)hh);
        if (j < 8) { uh0.h[j] = hh; ul0.h[j] = ll; }
        else       { uh1.h[j - 8] = hh; ul1.h[j - 8] = ll; }
    }
    *(uint4*)(Hhi + base)     = uh0.u;
    *(uint4*)(Hhi + base + 8) = uh1.u;
    *(uint4*)(Hlo + base)     = ul0.u;
    *(uint4*)(Hlo + base + 8) = ul1.u;
}

// ---------------------------------------------------------------------------
// 7) MFMA argmax: s'(t,k) = hhat.ehat + (-0.5*||ehat||^2).
// NOTE: dot MUST be accumulated from zero-init C and q added AFTER — this
// rounding order is bit-matched to the validated r6 kernel. Folding q into
// the C init (r7) perturbed near-ties between codebook rows at distant
// indices and flipped vq_code. Do not reassociate.
// grid (NT/256, 16 k-splits), block 256; prefetched E-tiles, 16 iters of 16.
__global__ __launch_bounds__(256) void k_argmax_mfma(const _Float16* __restrict__ Hhi,
                                                     const _Float16* __restrict__ Hlo,
                                                     const _Float16* __restrict__ Ehi,
                                                     const _Float16* __restrict__ Elo,
                                                     const float* __restrict__ eqh,
                                                     float* __restrict__ ps,
                                                     int* __restrict__ pi) {
    int tid = threadIdx.x;
    int wave = tid >> 6, lane = tid & 63;
    int l15 = lane & 15, quad = lane >> 4;
    int t0 = blockIdx.x * 256 + wave * 64;
    int kh = blockIdx.y;                  // 0..15, k-range [kh*256, kh*256+256)
    const int kbase = kh << 8;

    h8v hh0[4], hh1[4], hl0[4], hl1[4];
#pragma unroll
    for (int s = 0; s < 4; s++) {
        size_t hb = (size_t)(t0 + (s << 4) + l15) * 64 + (quad << 3);
        hh0[s] = *(const h8v*)(Hhi + hb);
        hh1[s] = *(const h8v*)(Hhi + hb + 32);
        hl0[s] = *(const h8v*)(Hlo + hb);
        hl1[s] = *(const h8v*)(Hlo + hb + 32);
    }
    float best[4] = {-1e30f, -1e30f, -1e30f, -1e30f};
    int   idx[4]  = {0, 0, 0, 0};

    // prefetch iteration 0
    size_t eb = (size_t)(kbase + l15) * 64 + (quad << 3);
    h8v eh0 = *(const h8v*)(Ehi + eb);
    h8v eh1 = *(const h8v*)(Ehi + eb + 32);
    h8v el0 = *(const h8v*)(Elo + eb);
    h8v el1 = *(const h8v*)(Elo + eb + 32);
    float4 q4 = *(const float4*)(eqh + kbase + (quad << 2));

    for (int it = 0; it < 16; it++) {
        h8v ce0 = eh0, ce1 = eh1, cl0 = el0, cl1 = el1;
        float4 cq = q4;
        int k0 = kbase + (it << 4);
        int kn = k0 + 16;
        if (kn > KK - 16) kn = KK - 16;       // last iter: redundant-but-valid load
        size_t ebn = (size_t)(kn + l15) * 64 + (quad << 3);
        eh0 = *(const h8v*)(Ehi + ebn);
        eh1 = *(const h8v*)(Ehi + ebn + 32);
        el0 = *(const h8v*)(Elo + ebn);
        el1 = *(const h8v*)(Elo + ebn + 32);
        q4 = *(const float4*)(eqh + kn + (quad << 2));

        f4v acc[4];
#pragma unroll
        for (int s = 0; s < 4; s++) acc[s] = (f4v){0.f, 0.f, 0.f, 0.f};
#pragma unroll
        for (int s = 0; s < 4; s++) acc[s] = __builtin_amdgcn_mfma_f32_16x16x32_f16(ce0, hh0[s], acc[s], 0, 0, 0);
#pragma unroll
        for (int s = 0; s < 4; s++) acc[s] = __builtin_amdgcn_mfma_f32_16x16x32_f16(ce1, hh1[s], acc[s], 0, 0, 0);
#pragma unroll
        for (int s = 0; s < 4; s++) acc[s] = __builtin_amdgcn_mfma_f32_16x16x32_f16(cl0, hh0[s], acc[s], 0, 0, 0);
#pragma unroll
        for (int s = 0; s < 4; s++) acc[s] = __builtin_amdgcn_mfma_f32_16x16x32_f16(cl1, hh1[s], acc[s], 0, 0, 0);
#pragma unroll
        for (int s = 0; s < 4; s++) acc[s] = __builtin_amdgcn_mfma_f32_16x16x32_f16(ce0, hl0[s], acc[s], 0, 0, 0);
#pragma unroll
        for (int s = 0; s < 4; s++) acc[s] = __builtin_amdgcn_mfma_f32_16x16x32_f16(ce1, hl1[s], acc[s], 0, 0, 0);
        float qv[4] = {cq.x, cq.y, cq.z, cq.w};
#pragma unroll
        for (int r = 0; r < 4; r++) {
            int k = k0 + (quad << 2) + r;
#pragma unroll
            for (int s = 0; s < 4; s++) {
                float sc = acc[s][r] + qv[r];
                if (sc > best[s]) { best[s] = sc; idx[s] = k; }
            }
        }
    }
#pragma unroll
    for (int m = 16; m <= 32; m <<= 1) {
#pragma unroll
        for (int s = 0; s < 4; s++) {
            float ob = __shfl_xor(best[s], m, 64);
            int   oi = __shfl_xor(idx[s], m, 64);
            if (ob > best[s] || (ob == best[s] && oi < idx[s])) { best[s] = ob; idx[s] = oi; }
        }
    }
    if (quad == 0) {
#pragma unroll
        for (int s = 0; s < 4; s++) {
            int t = t0 + (s << 4) + l15;
            ps[(size_t)t * 16 + kh] = best[s];
            pi[(size_t)t * 16 + kh] = idx[s];
        }
    }
}

// ---------------------------------------------------------------------------
// 8) merge 16 partials -> code; write vq_code (fp32, masked); gather G16 (f16)
__global__ __launch_bounds__(256) void k_merge(const float* __restrict__ ps,
                                               const int* __restrict__ pi,
                                               const int* __restrict__ mask,
                                               const _Float16* __restrict__ Ehi,
                                               _Float16* __restrict__ G16,
                                               float* __restrict__ outc) {
    __shared__ int codes[256];
    __shared__ int ms[256];
    int tid = threadIdx.x;
    int base = blockIdx.x << 8;
    int t = base + tid;
    float best = ps[(size_t)t * 16];
    int bi = pi[(size_t)t * 16];
#pragma unroll
    for (int s = 1; s < 16; s++) {
        float v = ps[(size_t)t * 16 + s];
        if (v > best) { best = v; bi = pi[(size_t)t * 16 + s]; }
    }
    int m = mask[t];
    codes[tid] = bi;
    ms[tid] = m;
    outc[t] = m ? (float)bi : 0.0f;
    __syncthreads();
    // 64 f16 per row = 8 uint4
    for (int i = tid; i < 256 * 8; i += 256) {
        int r = i >> 3, u = i & 7;
        uint4 e = ms[r] ? ((const uint4*)(Ehi + ((size_t)codes[r] << 6)))[u]
                        : make_uint4(0u, 0u, 0u, 0u);
        ((uint4*)(G16 + ((size_t)(base + r) << 6)))[u] = e;
    }
}

// ---------------------------------------------------------------------------
// 9) final projection: out_q[t][d] = sum_v G16[t][v]*iwh[d][v] + inv_b[d]
// 1-term f16 MFMA (not argmax-feeding; threshold very loose).
// grid (NT/128, DD/64), block 256 (4 waves, each 32t x 64d). K=64 (2 steps).
__global__ __launch_bounds__(256) void k_gemm_out(const _Float16* __restrict__ G16,
                                                  const _Float16* __restrict__ iwh,
                                                  const float* __restrict__ bias,
                                                  float* __restrict__ C) {
    const int tid = threadIdx.x;
    const int t0 = blockIdx.x * 128, n0 = blockIdx.y * 64;
    const int wave = tid >> 6, lane = tid & 63;
    const int l15 = lane & 15, quad = lane >> 4;

    f4v acc[2][4];
#pragma unroll
    for (int i = 0; i < 2; i++)
#pragma unroll
        for (int j = 0; j < 4; j++) acc[i][j] = (f4v){0.f, 0.f, 0.f, 0.f};

#pragma unroll
    for (int ks = 0; ks < 2; ks++) {
        int kk = (ks << 5) + (quad << 3);
        h8v a[2], b[4];
#pragma unroll
        for (int mt = 0; mt < 2; mt++)
            a[mt] = *(const h8v*)(G16 + (size_t)(t0 + (wave << 5) + (mt << 4) + l15) * 64 + kk);
#pragma unroll
        for (int nt = 0; nt < 4; nt++)
            b[nt] = *(const h8v*)(iwh + (size_t)(n0 + (nt << 4) + l15) * 64 + kk);
#pragma unroll
        for (int mt = 0; mt < 2; mt++)
#pragma unroll
            for (int nt = 0; nt < 4; nt++)
                acc[mt][nt] = __builtin_amdgcn_mfma_f32_16x16x32_f16(a[mt], b[nt], acc[mt][nt], 0, 0, 0);
    }
#pragma unroll
    for (int nt = 0; nt < 4; nt++) {
        int col = n0 + (nt << 4) + l15;
        float bv = bias[col];
#pragma unroll
        for (int mt = 0; mt < 2; mt++) {
            int row = t0 + (wave << 5) + (mt << 4) + (quad << 2);
#pragma unroll
            for (int r = 0; r < 4; r++)
                C[(size_t)(row + r) * DD + col] = acc[mt][nt][r] + bv;
        }
    }
}

// ---------------------------------------------------------------------------
extern "C" void kernel_launch(void* const* d_in, const int* in_sizes, int n_in,
                              void* d_out, int out_size, void* d_ws, size_t ws_size,
                              hipStream_t stream) {
    const float* h_in   = (const float*)d_in[0];
    const int*   amask  = (const int*)d_in[1];
    const float* proj_w = (const float*)d_in[2];
    const float* proj_b = (const float*)d_in[3];
    const float* inv_w  = (const float*)d_in[4];
    const float* inv_b  = (const float*)d_in[5];
    const float* w_in   = (const float*)d_in[6];
    const float* b_in   = (const float*)d_in[7];
    const float* w_mid  = (const float*)d_in[8];
    const float* b_mid  = (const float*)d_in[9];
    const float* w_out  = (const float*)d_in[10];
    const float* b_out  = (const float*)d_in[11];
    const float* gamma  = (const float*)d_in[12];
    const float* beta   = (const float*)d_in[13];

    // static region (high-water mark == r8-proven footprint; do NOT extend)
    float*     Y    = (float*)d_ws;                          // K*HID fp32   (16 MB)
    _Float16*  Xhi  = (_Float16*)(Y + (size_t)KK * HID_);    // K*HID fp16   (8 MB)
    _Float16*  Xlo  = Xhi + (size_t)KK * HID_;               // K*HID fp16   (8 MB)
    float*     mv   = (float*)(Xlo + (size_t)KK * HID_);     // 2*HID
    float*     Emb  = mv + 2 * HID_;                         // K*VQ fp32
    float*     eqh  = Emb + (size_t)KK * VQ_;                // K
    float*     spart= eqh + KK;                              // 2*64*1024 stats partials
    _Float16*  pwhi = (_Float16*)(spart + 2 * 65536);        // VQ*DD f16
    _Float16*  pwlo = pwhi + (size_t)VQ_ * DD;               // VQ*DD f16  <- ws END (r8 level)
    // overlays (inside dead Xhi/Xlo region, valid after the out-layer GEMM):
    float*    Hpart = Y;                                     // 4*NT*64 fp32 == K*HID exactly
    _Float16* H16hi = Xhi;                                   // NT*64 f16
    _Float16* H16lo = H16hi + (size_t)NT * VQ_;              // NT*64 f16
    _Float16* E16hi = H16lo + (size_t)NT * VQ_;              // K*64 f16
    _Float16* E16lo = E16hi + (size_t)KK * VQ_;              // K*64 f16
    float*    ps    = (float*)(E16lo + (size_t)KK * VQ_);    // NT*16
    int*      pidx  = (int*)(ps + (size_t)NT * 16);          // NT*16
    _Float16* G16   = (_Float16*)(pidx + (size_t)NT * 16);   // NT*64 f16
    _Float16* iwh   = G16 + (size_t)NT * VQ_;                // DD*VQ f16 (overlay, not ws end)

    float* out_q = (float*)d_out;                            // NT*DD fp32
    float* out_c = out_q + (size_t)NT * DD;                  // NT fp32

    // codebook MLP (fp16-split MFMA chain, fp32-equivalent precision)
    k_mlp_in<<<dim3(HID_ / 256, KK / 16), 256, 0, stream>>>(w_in, b_in, Y);
    k_bn_stats1<<<dim3(64, 4), 256, 0, stream>>>(Y, spart);
    k_bn_stats2<<<4, 256, 0, stream>>>(spart, mv);
    k_bn_apply_split<<<KK * HID_ / 1024, 256, 0, stream>>>(Y, mv, gamma, beta, Xhi, Xlo);
    for (int i = 0; i < NMID; i++) {
        k_gemm_mfma<<<dim3(KK / 128, HID_ / 64), 256, 0, stream>>>(
            Xhi, Xlo, w_mid + (size_t)i * HID_ * HID_, b_mid + (size_t)i * HID_, Y,
            KK, HID_, HID_);
        k_bn_stats1<<<dim3(64, 4), 256, 0, stream>>>(Y, spart);
        k_bn_stats2<<<4, 256, 0, stream>>>(spart, mv);
        k_bn_apply_split<<<KK * HID_ / 1024, 256, 0, stream>>>(Y, mv,
            gamma + (size_t)(i + 1) * HID_, beta + (size_t)(i + 1) * HID_, Xhi, Xlo);
    }
    k_gemm_mfma<<<dim3(KK / 128, VQ_ / 64), 256, 0, stream>>>(
        Xhi, Xlo, w_out, b_out, Emb, KK, VQ_, HID_);
    k_l2norm<<<KK / 4, 256, 0, stream>>>(Emb, eqh, E16hi, E16lo);

    // hidden-state path (Xhi/Xlo dead from here; overlay region valid)
    k_wsplit<<<VQ_ * DD / 1024, 256, 0, stream>>>(proj_w, pwhi, pwlo);
    k_cvt_inv<<<VQ_ * DD / 1024, 256, 0, stream>>>(inv_w, iwh);
    k_proj_mfma<<<dim3(NT / 128, 4), 256, 0, stream>>>(h_in, pwhi, pwlo, Hpart);
    k_hnorm<<<NT / 64, 256, 0, stream>>>(Hpart, proj_b, H16hi, H16lo);
    k_argmax_mfma<<<dim3(NT / 256, 16), 256, 0, stream>>>(
        H16hi, H16lo, E16hi, E16lo, eqh, ps, pidx);
    k_merge<<<NT / 256, 256, 0, stream>>>(ps, pidx, amask, E16hi, G16, out_c);
    k_gemm_out<<<dim3(NT / 128, DD / 64), 256, 0, stream>>>(G16, iwh, inv_b, out_q);
}